// Round 4
// baseline (982.054 us; speedup 1.0000x reference)
//
#include <hip/hip_runtime.h>
#include <math.h>

#define N_NODES 50000
#define N_EDGES 800000
#define DIN 128
#define NB_SCAN ((N_NODES + 255) / 256)

typedef unsigned short u16;
typedef unsigned int u32;
typedef short short8 __attribute__((ext_vector_type(8)));
typedef float f32x4 __attribute__((ext_vector_type(4)));

__device__ __forceinline__ u16 f2bf(float x) {
  u32 u = __float_as_uint(x);
  u32 r = (u + 0x7FFFu + ((u >> 16) & 1u)) >> 16;
  return (u16)r;
}
__device__ __forceinline__ float bf2f(u16 h) { return __uint_as_float(((u32)h) << 16); }
__device__ __forceinline__ u32 pack_split(float x) {
  u16 h = f2bf(x);
  u16 l = f2bf(x - bf2f(h));
  return ((u32)h << 16) | (u32)l;
}

__device__ __forceinline__ f32x4 mfma_bf16(short8 a, short8 b, f32x4 c) {
  return __builtin_amdgcn_mfma_f32_16x16x32_bf16(a, b, c, 0, 0, 0);
}

// swizzled byte offset within a [rows][64 bf16] tile (128B rows)
#define SWZ(row, kb) ((row) * 128 + ((kb) ^ (((row) & 7) << 4)))

// ---------------- graph setup ----------------

__global__ void k_deg(const int* __restrict__ dst, int* __restrict__ deg) {
  int e = blockIdx.x * blockDim.x + threadIdx.x;
  if (e < N_EDGES) atomicAdd(&deg[dst[e]], 1);
}

__global__ void k_scan_local(const int* __restrict__ deg, int* __restrict__ excl,
                             int* __restrict__ bsum) {
  __shared__ int sm[256];
  int tid = threadIdx.x;
  int i = blockIdx.x * 256 + tid;
  int v = (i < N_NODES) ? deg[i] : 0;
  sm[tid] = v;
  __syncthreads();
  for (int off = 1; off < 256; off <<= 1) {
    int t = (tid >= off) ? sm[tid - off] : 0;
    __syncthreads();
    sm[tid] += t;
    __syncthreads();
  }
  if (i < N_NODES) excl[i] = sm[tid] - v;
  if (tid == 255) bsum[blockIdx.x] = sm[255];
}

__global__ void k_scan_bsum(const int* __restrict__ bsum, int* __restrict__ boff,
                            int* __restrict__ row_off) {
  __shared__ int sm[256];
  int tid = threadIdx.x;
  int v = (tid < NB_SCAN) ? bsum[tid] : 0;
  sm[tid] = v;
  __syncthreads();
  for (int off = 1; off < 256; off <<= 1) {
    int t = (tid >= off) ? sm[tid - off] : 0;
    __syncthreads();
    sm[tid] += t;
    __syncthreads();
  }
  if (tid < NB_SCAN) boff[tid] = sm[tid] - v;
  if (tid == 255) row_off[N_NODES] = sm[255];
}

__global__ void k_scan_add(const int* __restrict__ excl, const int* __restrict__ boff,
                           int* __restrict__ row_off) {
  int i = blockIdx.x * 256 + threadIdx.x;
  if (i < N_NODES) row_off[i] = excl[i] + boff[i >> 8];
}

__global__ void k_node_init(const int* __restrict__ deg, const int* __restrict__ row_off,
                            int* __restrict__ cursor, float* __restrict__ amp,
                            float* __restrict__ att) {
  int v = blockIdx.x * blockDim.x + threadIdx.x;
  if (v >= N_NODES) return;
  cursor[v] = row_off[v];
  float d = (float)deg[v];
  float logd = logf(d + 1.0f);
  amp[v] = logd / 3.0f;
  att[v] = 3.0f / fmaxf(logd, 1e-6f);
}

__global__ void k_fill(const int* __restrict__ src, const int* __restrict__ dst,
                       int* __restrict__ cursor, int* __restrict__ nbr) {
  int e = blockIdx.x * blockDim.x + threadIdx.x;
  if (e >= N_EDGES) return;
  int slot = atomicAdd(&cursor[dst[e]], 1);
  nbr[slot] = src[e];
}

// ---------------- weight prep: transpose + split-bf16 ----------------

// WabT[j][k] = j<128 ? Mw[k][j] : Mw[128+k][j-128]
__global__ void k_prep_ab(const float* __restrict__ Mw, const float* __restrict__ Mb,
                          u16* __restrict__ Th, u16* __restrict__ Tl,
                          float* __restrict__ bias_ab) {
  int j = blockIdx.x;     // 0..255
  int k = threadIdx.x;    // 0..127
  float w = (j < 128) ? Mw[k * 128 + j] : Mw[(128 + k) * 128 + (j - 128)];
  u16 hi = f2bf(w);
  u16 lo = f2bf(w - bf2f(hi));
  Th[j * 128 + k] = hi;
  Tl[j * 128 + k] = lo;
  if (k == 0) bias_ab[j] = (j < 128) ? 0.f : Mb[j - 128];
}

// plane p, col j, k in [0,512): UT[p][j][k].
// p==0: Uw rows 0..511 (h | mean | min | max)
// p>0 : k>=128 -> Uw rows 512+384*(p-1)+(k-128) (amp / att blocks); k<128 unused
__global__ void k_prep_u(const float* __restrict__ Uw, u16* __restrict__ Th,
                         u16* __restrict__ Tl, int Nout) {
  int k = blockIdx.x * 256 + threadIdx.x;  // 0..511
  int j = blockIdx.y;
  int p = blockIdx.z;
  if (p > 0 && k < 128) return;
  int srow = (p == 0) ? k : 512 + 384 * (p - 1) + (k - 128);
  float w = Uw[(size_t)srow * Nout + j];
  u16 hi = f2bf(w);
  u16 lo = f2bf(w - bf2f(hi));
  size_t idx = ((size_t)p * Nout + j) * 512 + k;
  Th[idx] = hi;
  Tl[idx] = lo;
}

// ---------------- layer-0 x pack (Xp stride 512) ----------------

__global__ void k_pack_x(const float* __restrict__ x, u32* __restrict__ Xp) {
  int i = blockIdx.x * 256 + threadIdx.x;
  if (i >= N_NODES * DIN) return;
  int g = i >> 7, c = i & 127;
  Xp[(size_t)g * 512 + c] = pack_split(x[i]);
}

// ---------------- packed split-bf16 MFMA GEMM ----------------
// A = Xp[M][512] packed u32 (hi<<16|lo). B = WT[col][BS] hi/lo, rows=output cols.
// MODE 0: dual out (gc<128 -> bf16 ABa ; gc>=128 -> fp32 ABb + bias)
// MODE 1: P = acc + bias
// MODE 2: P += scale[row] * acc
// MODE 3: outF = P + scale[row] * acc

template <int BN, int MODE>
__global__ __launch_bounds__(256) void k_mfma_gemm(
    const u32* __restrict__ Xp, const u16* __restrict__ WTh,
    const u16* __restrict__ WTl, const float* __restrict__ bias,
    const float* __restrict__ scale, float* __restrict__ P,
    u16* __restrict__ outA, float* __restrict__ outB, float* __restrict__ outF,
    int K, int kstart, int BS, int Nout) {
  __shared__ __align__(16) u16 Ah[128 * 64];
  __shared__ __align__(16) u16 Al[128 * 64];
  __shared__ __align__(16) u16 Bh[BN * 64];
  __shared__ __align__(16) u16 Bl[BN * 64];

  const int tid = threadIdx.x;
  const int row0 = blockIdx.x * 128;
  const int col0 = blockIdx.y * BN;
  const int lane = tid & 63;
  const int wave = tid >> 6;
  const int wrow = (wave >> 1) * 64;
  const int wcol = (wave & 1) * (BN / 2);
  constexpr int NREP = BN / 32;

  f32x4 acc[4][NREP];
  const f32x4 zero4 = {0.f, 0.f, 0.f, 0.f};
#pragma unroll
  for (int i = 0; i < 4; ++i)
#pragma unroll
    for (int n = 0; n < NREP; ++n) acc[i][n] = zero4;

  const int sm_ = tid >> 4;          // A-stage sub-row 0..15
  const int skq = (tid & 15) * 4;    // A-stage elem offset

  for (int k0 = kstart; k0 < K; k0 += 64) {
    __syncthreads();
    // ---- stage A: pure copy + hi/lo unzip via v_perm ----
#pragma unroll
    for (int r = 0; r < 8; ++r) {
      int m = r * 16 + sm_;
      int g = row0 + m;
      uint4 p = {0u, 0u, 0u, 0u};
      if (g < N_NODES) p = *(const uint4*)(Xp + (size_t)g * 512 + k0 + skq);
      uint2 hv, lv;
      hv.x = __builtin_amdgcn_perm(p.y, p.x, 0x07060302u);
      lv.x = __builtin_amdgcn_perm(p.y, p.x, 0x05040100u);
      hv.y = __builtin_amdgcn_perm(p.w, p.z, 0x07060302u);
      lv.y = __builtin_amdgcn_perm(p.w, p.z, 0x05040100u);
      int ad = SWZ(m, skq * 2);
      *(uint2*)((char*)Ah + ad) = hv;
      *(uint2*)((char*)Al + ad) = lv;
    }
    // ---- stage B: pure copy of pre-split weights ----
#pragma unroll
    for (int r = 0; r < BN / 32; ++r) {
      int op = r * 256 + tid;
      int c = op >> 3, sl = op & 7;
      const u16* srch = WTh + (size_t)(col0 + c) * BS + k0 + sl * 8;
      const u16* srcl = WTl + (size_t)(col0 + c) * BS + k0 + sl * 8;
      int bd = SWZ(c, sl * 16);
      *(uint4*)((char*)Bh + bd) = *(const uint4*)srch;
      *(uint4*)((char*)Bl + bd) = *(const uint4*)srcl;
    }
    __syncthreads();
    // ---- MFMA: 3-product split (hh + hl + lh) ----
#pragma unroll
    for (int kk = 0; kk < 2; ++kk) {
      const int kb = kk * 64 + (lane >> 4) * 16;
      short8 a_h[4], a_l[4];
#pragma unroll
      for (int i = 0; i < 4; ++i) {
        int rr = wrow + i * 16 + (lane & 15);
        a_h[i] = *(const short8*)((const char*)Ah + SWZ(rr, kb));
        a_l[i] = *(const short8*)((const char*)Al + SWZ(rr, kb));
      }
#pragma unroll
      for (int n = 0; n < NREP; ++n) {
        int cc = wcol + n * 16 + (lane & 15);
        short8 b_h = *(const short8*)((const char*)Bh + SWZ(cc, kb));
        short8 b_l = *(const short8*)((const char*)Bl + SWZ(cc, kb));
#pragma unroll
        for (int i = 0; i < 4; ++i) {
          acc[i][n] = mfma_bf16(a_h[i], b_h, acc[i][n]);
          acc[i][n] = mfma_bf16(a_h[i], b_l, acc[i][n]);
          acc[i][n] = mfma_bf16(a_l[i], b_h, acc[i][n]);
        }
      }
    }
  }
  // ---- epilogue ----
#pragma unroll
  for (int i = 0; i < 4; ++i) {
#pragma unroll
    for (int n = 0; n < NREP; ++n) {
      int gr0 = row0 + wrow + i * 16 + (lane >> 4) * 4;
      int gc = col0 + wcol + n * 16 + (lane & 15);
#pragma unroll
      for (int q = 0; q < 4; ++q) {
        int gr = gr0 + q;
        if (gr >= N_NODES) continue;
        float v = acc[i][n][q];
        if (MODE == 0) {
          if (gc < 128) outA[(size_t)gr * 128 + gc] = f2bf(v);
          else outB[(size_t)gr * 128 + (gc - 128)] = v + bias[gc];
        } else if (MODE == 1) {
          P[(size_t)gr * Nout + gc] = v + bias[gc];
        } else if (MODE == 2) {
          P[(size_t)gr * Nout + gc] += scale[gr] * v;
        } else {
          outF[(size_t)gr * Nout + gc] = P[(size_t)gr * Nout + gc] + scale[gr] * v;
        }
      }
    }
  }
}

// ---------------- aggregation: one wave per node, writes packed agg into Xp ----------------

__global__ __launch_bounds__(256) void k_agg(const u16* __restrict__ ABa,
                                             const float* __restrict__ ABb,
                                             const int* __restrict__ row_off,
                                             const int* __restrict__ nbr,
                                             u32* __restrict__ Xp) {
  int v = blockIdx.x * 4 + (threadIdx.x >> 6);
  int lane = threadIdx.x & 63;
  if (v >= N_NODES) return;
  int beg = row_off[v], end = row_off[v + 1];
  const u32* A32 = (const u32*)ABa;  // [N][64] u32, 2 bf16 cols each
  float sx = 0.f, sy = 0.f;
  float mnx = 3.4e38f, mny = 3.4e38f;
  float mxx = -3.4e38f, mxy = -3.4e38f;
  for (int i = beg; i < end; ++i) {
    int s = nbr[i];
    u32 w = A32[(size_t)s * 64 + lane];
    float ax = bf2f((u16)w), ay = bf2f((u16)(w >> 16));
    sx += ax; sy += ay;
    mnx = fminf(mnx, ax); mny = fminf(mny, ay);
    mxx = fmaxf(mxx, ax); mxy = fmaxf(mxy, ay);
  }
  int d = end - beg;
  int c = lane * 2;
  float2 b = *(const float2*)&ABb[(size_t)v * 128 + c];
  float mex, mey, mix, miy, max_, may_;
  if (d > 0) {
    float inv = 1.f / (float)d;
    mex = sx * inv + b.x; mey = sy * inv + b.y;
    mix = mnx + b.x; miy = mny + b.y;
    max_ = mxx + b.x; may_ = mxy + b.y;
  } else {
    mex = mey = mix = miy = max_ = may_ = 0.f;
  }
  u32* xr = Xp + (size_t)v * 512 + 128;
  uint2 t;
#define ST(off, X, Y) t.x = pack_split(X); t.y = pack_split(Y); *(uint2*)(xr + (off) + c) = t;
  ST(0, mex, mey)
  ST(128, mix, miy)
  ST(256, max_, may_)
#undef ST
}

// ---------------- combine: relu + pack next-layer h into Xp ----------------

__global__ void k_combine(const float* __restrict__ P, u32* __restrict__ Xp) {
  int i = blockIdx.x * 256 + threadIdx.x;
  if (i >= N_NODES * 128) return;
  int r = i >> 7, c = i & 127;
  Xp[(size_t)r * 512 + c] = pack_split(fmaxf(P[i], 0.f));
}

// ---------------- launch ----------------

extern "C" void kernel_launch(void* const* d_in, const int* in_sizes, int n_in,
                              void* d_out, int out_size, void* d_ws, size_t ws_size,
                              hipStream_t stream) {
  const float* x   = (const float*)d_in[0];
  const int*   src = (const int*)d_in[1];
  const int*   dst = (const int*)d_in[2];
  const float* Mw[3] = {(const float*)d_in[3], (const float*)d_in[7],  (const float*)d_in[11]};
  const float* Mb[3] = {(const float*)d_in[4], (const float*)d_in[8],  (const float*)d_in[12]};
  const float* Uw[3] = {(const float*)d_in[5], (const float*)d_in[9],  (const float*)d_in[13]};
  const float* Ub[3] = {(const float*)d_in[6], (const float*)d_in[10], (const float*)d_in[14]};
  float* out = (float*)d_out;

  char* ws = (char*)d_ws;
  size_t o = 0;
  auto alloc = [&](size_t bytes) -> char* {
    o = (o + 255) & ~(size_t)255;
    char* p = ws + o;
    o += bytes;
    return p;
  };
  int*   deg_i   = (int*)alloc((size_t)N_NODES * 4);
  int*   row_off = (int*)alloc((size_t)(N_NODES + 1) * 4);
  int*   excl    = (int*)alloc((size_t)N_NODES * 4);
  int*   bsum    = (int*)alloc((size_t)NB_SCAN * 4);
  int*   boff    = (int*)alloc((size_t)NB_SCAN * 4);
  int*   cursor  = (int*)alloc((size_t)N_NODES * 4);
  float* amp     = (float*)alloc((size_t)N_NODES * 4);
  float* att     = (float*)alloc((size_t)N_NODES * 4);
  int*   nbr     = (int*)alloc((size_t)N_EDGES * 4);
  u32*   Xp      = (u32*)alloc((size_t)N_NODES * 512 * 4);          // 102.4 MB
  char*  Ureg    = alloc((size_t)N_NODES * 128 * 2 + (size_t)N_NODES * 128 * 4);  // 38.4 MB
  u16*   ABa     = (u16*)Ureg;                                       // [N][128] bf16
  float* ABb     = (float*)(Ureg + (size_t)N_NODES * 128 * 2);       // [N][128] f32
  float* P       = (float*)Ureg;                                     // [N][<=128] f32 (alias, disjoint lifetime)
  u16*   WabTh[3]; u16* WabTl[3]; float* bias_ab[3];
  u16*   UTh[3];   u16* UTl[3];
  const int Nouts[3] = {128, 128, 64};
  for (int L = 0; L < 3; ++L) {
    WabTh[L] = (u16*)alloc((size_t)256 * 128 * 2);
    WabTl[L] = (u16*)alloc((size_t)256 * 128 * 2);
    bias_ab[L] = (float*)alloc(256 * 4);
    UTh[L] = (u16*)alloc((size_t)3 * Nouts[L] * 512 * 2);
    UTl[L] = (u16*)alloc((size_t)3 * Nouts[L] * 512 * 2);
  }

  // ---- graph structure ----
  hipMemsetAsync(deg_i, 0, (size_t)N_NODES * 4, stream);
  k_deg<<<(N_EDGES + 255) / 256, 256, 0, stream>>>(dst, deg_i);
  k_scan_local<<<NB_SCAN, 256, 0, stream>>>(deg_i, excl, bsum);
  k_scan_bsum<<<1, 256, 0, stream>>>(bsum, boff, row_off);
  k_scan_add<<<NB_SCAN, 256, 0, stream>>>(excl, boff, row_off);
  k_node_init<<<(N_NODES + 255) / 256, 256, 0, stream>>>(deg_i, row_off, cursor, amp, att);
  k_fill<<<(N_EDGES + 255) / 256, 256, 0, stream>>>(src, dst, cursor, nbr);

  // ---- weight prep + x pack ----
  for (int L = 0; L < 3; ++L) {
    k_prep_ab<<<256, 128, 0, stream>>>(Mw[L], Mb[L], WabTh[L], WabTl[L], bias_ab[L]);
    k_prep_u<<<dim3(2, Nouts[L], 3), 256, 0, stream>>>(Uw[L], UTh[L], UTl[L], Nouts[L]);
  }
  k_pack_x<<<(N_NODES * DIN + 255) / 256, 256, 0, stream>>>(x, Xp);

  const int MT = (N_NODES + 127) / 128;  // 391

  for (int L = 0; L < 3; ++L) {
    const int Nout = Nouts[L];
    const size_t psz = (size_t)Nout * 512;
    // AB = h @ [Mw_top | Mw_bot] (A-half bf16, B-half fp32+Mb)
    k_mfma_gemm<128, 0><<<dim3(MT, 2), 256, 0, stream>>>(
        Xp, WabTh[L], WabTl[L], bias_ab[L], nullptr, nullptr, ABa, ABb, nullptr,
        128, 0, 128, 256);
    k_agg<<<(N_NODES + 3) / 4, 256, 0, stream>>>(ABa, ABb, row_off, nbr, Xp);
    if (L < 2) {
      k_mfma_gemm<128, 1><<<dim3(MT, 1), 256, 0, stream>>>(
          Xp, UTh[L], UTl[L], Ub[L], nullptr, P, nullptr, nullptr, nullptr,
          512, 0, 512, Nout);
      k_mfma_gemm<128, 2><<<dim3(MT, 1), 256, 0, stream>>>(
          Xp, UTh[L] + psz, UTl[L] + psz, nullptr, amp, P, nullptr, nullptr, nullptr,
          512, 128, 512, Nout);
      k_mfma_gemm<128, 2><<<dim3(MT, 1), 256, 0, stream>>>(
          Xp, UTh[L] + 2 * psz, UTl[L] + 2 * psz, nullptr, att, P, nullptr, nullptr, nullptr,
          512, 128, 512, Nout);
      k_combine<<<(N_NODES * 128 + 255) / 256, 256, 0, stream>>>(P, Xp);
    } else {
      k_mfma_gemm<64, 1><<<dim3(MT, 1), 256, 0, stream>>>(
          Xp, UTh[L], UTl[L], Ub[L], nullptr, P, nullptr, nullptr, nullptr,
          512, 0, 512, Nout);
      k_mfma_gemm<64, 2><<<dim3(MT, 1), 256, 0, stream>>>(
          Xp, UTh[L] + psz, UTl[L] + psz, nullptr, amp, P, nullptr, nullptr, nullptr,
          512, 128, 512, Nout);
      k_mfma_gemm<64, 3><<<dim3(MT, 1), 256, 0, stream>>>(
          Xp, UTh[L] + 2 * psz, UTl[L] + 2 * psz, nullptr, att, P, nullptr, nullptr, out,
          512, 128, 512, Nout);
    }
  }
}

// Round 6
// 697.016 us; speedup vs baseline: 1.4089x; 1.4089x over previous
//
#include <hip/hip_runtime.h>
#include <math.h>

#define N_NODES 50000
#define N_EDGES 800000
#define DIN 128
#define NB_SCAN ((N_NODES + 255) / 256)

typedef unsigned short u16;
typedef unsigned int u32;
typedef short short8 __attribute__((ext_vector_type(8)));
typedef float f32x4 __attribute__((ext_vector_type(4)));

__device__ __forceinline__ u16 f2bf(float x) {
  u32 u = __float_as_uint(x);
  u32 r = (u + 0x7FFFu + ((u >> 16) & 1u)) >> 16;
  return (u16)r;
}
__device__ __forceinline__ float bf2f(u16 h) { return __uint_as_float(((u32)h) << 16); }
__device__ __forceinline__ u32 pack2bf(float x, float y) {
  return (u32)f2bf(x) | ((u32)f2bf(y) << 16);
}

__device__ __forceinline__ f32x4 mfma_bf16(short8 a, short8 b, f32x4 c) {
  return __builtin_amdgcn_mfma_f32_16x16x32_bf16(a, b, c, 0, 0, 0);
}

// swizzled BYTE offset within a [rows][64 bf16] LDS tile (128B rows)
#define SWZ(row, byt) ((row) * 128 + ((byt) ^ (((row) & 7) << 4)))

// ---------------- graph setup ----------------

__global__ void k_deg(const int* __restrict__ dst, int* __restrict__ deg) {
  int e = blockIdx.x * blockDim.x + threadIdx.x;
  if (e < N_EDGES) atomicAdd(&deg[dst[e]], 1);
}

__global__ void k_scan_local(const int* __restrict__ deg, int* __restrict__ excl,
                             int* __restrict__ bsum) {
  __shared__ int sm[256];
  int tid = threadIdx.x;
  int i = blockIdx.x * 256 + tid;
  int v = (i < N_NODES) ? deg[i] : 0;
  sm[tid] = v;
  __syncthreads();
  for (int off = 1; off < 256; off <<= 1) {
    int t = (tid >= off) ? sm[tid - off] : 0;
    __syncthreads();
    sm[tid] += t;
    __syncthreads();
  }
  if (i < N_NODES) excl[i] = sm[tid] - v;
  if (tid == 255) bsum[blockIdx.x] = sm[255];
}

__global__ void k_scan_bsum(const int* __restrict__ bsum, int* __restrict__ boff,
                            int* __restrict__ row_off) {
  __shared__ int sm[256];
  int tid = threadIdx.x;
  int v = (tid < NB_SCAN) ? bsum[tid] : 0;
  sm[tid] = v;
  __syncthreads();
  for (int off = 1; off < 256; off <<= 1) {
    int t = (tid >= off) ? sm[tid - off] : 0;
    __syncthreads();
    sm[tid] += t;
    __syncthreads();
  }
  if (tid < NB_SCAN) boff[tid] = sm[tid] - v;
  if (tid == 255) row_off[N_NODES] = sm[255];
}

__global__ void k_scan_add(const int* __restrict__ excl, const int* __restrict__ boff,
                           int* __restrict__ row_off) {
  int i = blockIdx.x * 256 + threadIdx.x;
  if (i < N_NODES) row_off[i] = excl[i] + boff[i >> 8];
}

__global__ void k_node_init(const int* __restrict__ deg, const int* __restrict__ row_off,
                            int* __restrict__ cursor, float* __restrict__ amp,
                            float* __restrict__ att) {
  int v = blockIdx.x * blockDim.x + threadIdx.x;
  if (v >= N_NODES) return;
  cursor[v] = row_off[v];
  float d = (float)deg[v];
  float logd = logf(d + 1.0f);
  amp[v] = logd / 3.0f;
  att[v] = 3.0f / fmaxf(logd, 1e-6f);
}

__global__ void k_fill(const int* __restrict__ src, const int* __restrict__ dst,
                       int* __restrict__ cursor, int* __restrict__ nbr) {
  int e = blockIdx.x * blockDim.x + threadIdx.x;
  if (e >= N_EDGES) return;
  int slot = atomicAdd(&cursor[dst[e]], 1);
  nbr[slot] = src[e];
}

// ---------------- weight prep ----------------

// WabT[j][k] = j<128 ? Mw[k][j] : Mw[128+k][j-128]   ([256][128] hi/lo)
__global__ void k_prep_ab(const float* __restrict__ Mw, const float* __restrict__ Mb,
                          u16* __restrict__ Th, u16* __restrict__ Tl,
                          float* __restrict__ bias_ab) {
  int j = blockIdx.x;     // 0..255
  int k = threadIdx.x;    // 0..127
  float w = (j < 128) ? Mw[k * 128 + j] : Mw[(128 + k) * 128 + (j - 128)];
  u16 hi = f2bf(w);
  u16 lo = f2bf(w - bf2f(hi));
  Th[j * 128 + k] = hi;
  Tl[j * 128 + k] = lo;
  if (k == 0) bias_ab[j] = (j < 128) ? 0.f : Mb[j - 128];
}

// UT[p][j][k], k in [0,512): p==0 -> Uw rows 0..511; p>0, k>=128 -> Uw rows 512+384*(p-1)+(k-128)
__global__ void k_prep_u(const float* __restrict__ Uw, u16* __restrict__ Th,
                         u16* __restrict__ Tl, int Nout) {
  int k = blockIdx.x * 256 + threadIdx.x;  // 0..511
  int j = blockIdx.y;
  int p = blockIdx.z;
  if (p > 0 && k < 128) return;
  int srow = (p == 0) ? k : 512 + 384 * (p - 1) + (k - 128);
  float w = Uw[(size_t)srow * Nout + j];
  u16 hi = f2bf(w);
  u16 lo = f2bf(w - bf2f(hi));
  size_t idx = ((size_t)p * Nout + j) * 512 + k;
  Th[idx] = hi;
  Tl[idx] = lo;
}

// ---------------- layer-0 x pack: Xh (hi, stride 512) + Xl (lo, stride 128) ----------------

__global__ void k_pack_x(const float* __restrict__ x, u16* __restrict__ Xh,
                         u16* __restrict__ Xl) {
  int i = blockIdx.x * 256 + threadIdx.x;
  if (i >= N_NODES * DIN) return;
  int g = i >> 7, c = i & 127;
  float v = x[i];
  u16 hi = f2bf(v);
  Xh[(size_t)g * 512 + c] = hi;
  Xl[(size_t)g * 128 + c] = f2bf(v - bf2f(hi));
}

// ---------------- AB GEMM: [N][256] = h @ [Mw_top | Mw_bot] ----------------
// Reads XhIn/XlIn only. Writes ABa (bf16, cols<128) / ABb (f32+bias, cols>=128).

__global__ __launch_bounds__(256) void k_ab_gemm(
    const u16* __restrict__ Xh, const u16* __restrict__ Xl,
    const u16* __restrict__ WTh, const u16* __restrict__ WTl,
    const float* __restrict__ bias, u16* __restrict__ ABa, float* __restrict__ ABb) {
  __shared__ __align__(16) u16 Ah[128 * 64];
  __shared__ __align__(16) u16 Al[128 * 64];
  __shared__ __align__(16) u16 Bh[128 * 64];
  __shared__ __align__(16) u16 Bl[128 * 64];

  const int tid = threadIdx.x;
  const int row0 = blockIdx.x * 128;
  const int col0 = blockIdx.y * 128;
  const int lane = tid & 63;
  const int wave = tid >> 6;
  const int wrow = (wave >> 1) * 64;
  const int wcol = (wave & 1) * 64;

  f32x4 acc[4][4];
  const f32x4 zero4 = {0.f, 0.f, 0.f, 0.f};
#pragma unroll
  for (int i = 0; i < 4; ++i)
#pragma unroll
    for (int n = 0; n < 4; ++n) acc[i][n] = zero4;

  for (int k0 = 0; k0 < 128; k0 += 64) {
    __syncthreads();
#pragma unroll
    for (int r = 0; r < 4; ++r) {  // A: 128 rows x 8 chunks(16B)
      int op = r * 256 + tid;
      int m = op >> 3, ch = op & 7;
      int g = row0 + m;
      uint4 hv = {0u, 0u, 0u, 0u}, lv = {0u, 0u, 0u, 0u};
      if (g < N_NODES) {
        hv = *(const uint4*)(Xh + (size_t)g * 512 + k0 + ch * 8);
        lv = *(const uint4*)(Xl + (size_t)g * 128 + k0 + ch * 8);
      }
      int ad = SWZ(m, ch * 16);
      *(uint4*)((char*)Ah + ad) = hv;
      *(uint4*)((char*)Al + ad) = lv;
    }
#pragma unroll
    for (int r = 0; r < 4; ++r) {  // B: 128 cols x 8 chunks
      int op = r * 256 + tid;
      int c = op >> 3, sl = op & 7;
      int bd = SWZ(c, sl * 16);
      *(uint4*)((char*)Bh + bd) = *(const uint4*)(WTh + (size_t)(col0 + c) * 128 + k0 + sl * 8);
      *(uint4*)((char*)Bl + bd) = *(const uint4*)(WTl + (size_t)(col0 + c) * 128 + k0 + sl * 8);
    }
    __syncthreads();
#pragma unroll
    for (int kk = 0; kk < 2; ++kk) {
      const int kb = kk * 64 + (lane >> 4) * 16;
      short8 a_h[4], a_l[4];
#pragma unroll
      for (int i = 0; i < 4; ++i) {
        int rr = wrow + i * 16 + (lane & 15);
        a_h[i] = *(const short8*)((const char*)Ah + SWZ(rr, kb));
        a_l[i] = *(const short8*)((const char*)Al + SWZ(rr, kb));
      }
#pragma unroll
      for (int n = 0; n < 4; ++n) {
        int cc = wcol + n * 16 + (lane & 15);
        short8 b_h = *(const short8*)((const char*)Bh + SWZ(cc, kb));
        short8 b_l = *(const short8*)((const char*)Bl + SWZ(cc, kb));
#pragma unroll
        for (int i = 0; i < 4; ++i) {
          acc[i][n] = mfma_bf16(a_h[i], b_h, acc[i][n]);
          acc[i][n] = mfma_bf16(a_h[i], b_l, acc[i][n]);
          acc[i][n] = mfma_bf16(a_l[i], b_h, acc[i][n]);
        }
      }
    }
  }
#pragma unroll
  for (int i = 0; i < 4; ++i) {
#pragma unroll
    for (int n = 0; n < 4; ++n) {
      int gr0 = row0 + wrow + i * 16 + (lane >> 4) * 4;
      int gc = col0 + wcol + n * 16 + (lane & 15);
#pragma unroll
      for (int q = 0; q < 4; ++q) {
        int gr = gr0 + q;
        if (gr >= N_NODES) continue;
        float v = acc[i][n][q];
        if (gc < 128) ABa[(size_t)gr * 128 + gc] = f2bf(v);
        else ABb[(size_t)gr * 128 + (gc - 128)] = v + bias[gc];
      }
    }
  }
}

// ---------------- fused U GEMM: 3 plane-spans, register merge ----------------
// Reads XhIn/XlIn (ping). Writes XhOut/XlOut (pong) or outF. NO in-place.

template <int BN, int LAST>
__global__ __launch_bounds__(256, 2) void k_u_fused(
    const u16* __restrict__ Xh, const u16* __restrict__ Xl,
    const u16* __restrict__ UTh, const u16* __restrict__ UTl,
    const float* __restrict__ Ub, const float* __restrict__ amp,
    const float* __restrict__ att, u16* __restrict__ XhW, u16* __restrict__ XlW,
    float* __restrict__ outF, int Nout) {
  __shared__ __align__(16) u16 Ah[128 * 64];
  __shared__ __align__(16) u16 Al[128 * 64];
  __shared__ __align__(16) u16 Bh[BN * 64];
  __shared__ __align__(16) u16 Bl[BN * 64];

  const int tid = threadIdx.x;
  const int row0 = blockIdx.x * 128;
  const int lane = tid & 63;
  const int wave = tid >> 6;
  const int wrow = (wave >> 1) * 64;
  const int wcol = (wave & 1) * (BN / 2);
  constexpr int NREP = BN / 32;

  f32x4 acc_t[4][NREP], acc_p[4][NREP];
  const f32x4 zero4 = {0.f, 0.f, 0.f, 0.f};
#pragma unroll
  for (int i = 0; i < 4; ++i)
#pragma unroll
    for (int n = 0; n < NREP; ++n) acc_t[i][n] = zero4;

  for (int span = 0; span < 3; ++span) {
    const u16* BTh = UTh + (size_t)span * Nout * 512;
    const u16* BTl = UTl + (size_t)span * Nout * 512;
    const int kbeg = (span == 0) ? 0 : 128;
#pragma unroll
    for (int i = 0; i < 4; ++i)
#pragma unroll
      for (int n = 0; n < NREP; ++n) acc_p[i][n] = zero4;

    for (int k0 = kbeg; k0 < 512; k0 += 64) {
      const bool hstep = (k0 < 128);  // uniform
      __syncthreads();
#pragma unroll
      for (int r = 0; r < 4; ++r) {  // A hi (+lo if hstep)
        int op = r * 256 + tid;
        int m = op >> 3, ch = op & 7;
        int g = row0 + m;
        int ad = SWZ(m, ch * 16);
        uint4 hv = {0u, 0u, 0u, 0u};
        if (g < N_NODES) hv = *(const uint4*)(Xh + (size_t)g * 512 + k0 + ch * 8);
        *(uint4*)((char*)Ah + ad) = hv;
        if (hstep) {
          uint4 lv = {0u, 0u, 0u, 0u};
          if (g < N_NODES) lv = *(const uint4*)(Xl + (size_t)g * 128 + k0 + ch * 8);
          *(uint4*)((char*)Al + ad) = lv;
        }
      }
#pragma unroll
      for (int r = 0; r < NREP; ++r) {  // B: BN cols x 8 chunks
        int op = r * 256 + tid;
        int c = op >> 3, sl = op & 7;
        int bd = SWZ(c, sl * 16);
        *(uint4*)((char*)Bh + bd) = *(const uint4*)(BTh + (size_t)c * 512 + k0 + sl * 8);
        *(uint4*)((char*)Bl + bd) = *(const uint4*)(BTl + (size_t)c * 512 + k0 + sl * 8);
      }
      __syncthreads();
#pragma unroll
      for (int kk = 0; kk < 2; ++kk) {
        const int kb = kk * 64 + (lane >> 4) * 16;
        short8 a_h[4], a_l[4];
#pragma unroll
        for (int i = 0; i < 4; ++i) {
          int rr = wrow + i * 16 + (lane & 15);
          a_h[i] = *(const short8*)((const char*)Ah + SWZ(rr, kb));
          if (hstep) a_l[i] = *(const short8*)((const char*)Al + SWZ(rr, kb));
        }
#pragma unroll
        for (int n = 0; n < NREP; ++n) {
          int cc = wcol + n * 16 + (lane & 15);
          short8 b_h = *(const short8*)((const char*)Bh + SWZ(cc, kb));
          short8 b_l = *(const short8*)((const char*)Bl + SWZ(cc, kb));
#pragma unroll
          for (int i = 0; i < 4; ++i) {
            acc_p[i][n] = mfma_bf16(a_h[i], b_h, acc_p[i][n]);
            acc_p[i][n] = mfma_bf16(a_h[i], b_l, acc_p[i][n]);
            if (hstep) acc_p[i][n] = mfma_bf16(a_l[i], b_h, acc_p[i][n]);
          }
        }
      }
    }
    // merge span into total
    if (span == 0) {
#pragma unroll
      for (int i = 0; i < 4; ++i)
#pragma unroll
        for (int n = 0; n < NREP; ++n) acc_t[i][n] += acc_p[i][n];
    } else {
      const float* sc = (span == 1) ? amp : att;
#pragma unroll
      for (int i = 0; i < 4; ++i) {
        int gr0 = row0 + wrow + i * 16 + (lane >> 4) * 4;
        f32x4 sv = *(const f32x4*)(sc + gr0);
#pragma unroll
        for (int n = 0; n < NREP; ++n)
#pragma unroll
          for (int q = 0; q < 4; ++q) acc_t[i][n][q] += sv[q] * acc_p[i][n][q];
      }
    }
  }
  // epilogue
#pragma unroll
  for (int i = 0; i < 4; ++i) {
#pragma unroll
    for (int n = 0; n < NREP; ++n) {
      int gr0 = row0 + wrow + i * 16 + (lane >> 4) * 4;
      int gc = wcol + n * 16 + (lane & 15);
      float b = Ub[gc];
#pragma unroll
      for (int q = 0; q < 4; ++q) {
        int gr = gr0 + q;
        if (gr >= N_NODES) continue;
        float v = acc_t[i][n][q] + b;
        if (LAST) {
          outF[(size_t)gr * 64 + gc] = v;
        } else {
          float t = fmaxf(v, 0.f);
          u16 hi = f2bf(t);
          XhW[(size_t)gr * 512 + gc] = hi;
          XlW[(size_t)gr * 128 + gc] = f2bf(t - bf2f(hi));
        }
      }
    }
  }
}

// ---------------- aggregation: one wave/node. Reads ABa/ABb, WRITES XhDst cols 128..511 ----------------

__global__ __launch_bounds__(256) void k_agg(const u16* __restrict__ ABa,
                                             const float* __restrict__ ABb,
                                             const int* __restrict__ row_off,
                                             const int* __restrict__ nbr,
                                             u16* __restrict__ XhDst) {
  int v = blockIdx.x * 4 + (threadIdx.x >> 6);
  int lane = threadIdx.x & 63;
  if (v >= N_NODES) return;
  int beg = row_off[v], end = row_off[v + 1];
  const u32* A32 = (const u32*)ABa;  // [N][64] u32 (2 bf16 each)
  float sx = 0.f, sy = 0.f;
  float mnx = 3.4e38f, mny = 3.4e38f;
  float mxx = -3.4e38f, mxy = -3.4e38f;
  int i = beg;
#define ACC(w)                                              \
  {                                                         \
    float ax = bf2f((u16)(w)), ay = bf2f((u16)((w) >> 16)); \
    sx += ax; sy += ay;                                     \
    mnx = fminf(mnx, ax); mny = fminf(mny, ay);             \
    mxx = fmaxf(mxx, ax); mxy = fmaxf(mxy, ay);             \
  }
  for (; i + 4 <= end; i += 4) {
    int s0 = nbr[i], s1 = nbr[i + 1], s2 = nbr[i + 2], s3 = nbr[i + 3];
    u32 w0 = A32[(size_t)s0 * 64 + lane];
    u32 w1 = A32[(size_t)s1 * 64 + lane];
    u32 w2 = A32[(size_t)s2 * 64 + lane];
    u32 w3 = A32[(size_t)s3 * 64 + lane];
    ACC(w0) ACC(w1) ACC(w2) ACC(w3)
  }
  for (; i < end; ++i) {
    u32 w = A32[(size_t)nbr[i] * 64 + lane];
    ACC(w)
  }
#undef ACC
  int d = end - beg;
  int c = lane * 2;
  float2 b = *(const float2*)&ABb[(size_t)v * 128 + c];
  float mex, mey, mix, miy, max_, may_;
  if (d > 0) {
    float inv = 1.f / (float)d;
    mex = sx * inv + b.x; mey = sy * inv + b.y;
    mix = mnx + b.x; miy = mny + b.y;
    max_ = mxx + b.x; may_ = mxy + b.y;
  } else {
    mex = mey = mix = miy = max_ = may_ = 0.f;
  }
  u16* xr = XhDst + (size_t)v * 512 + 128 + c;
  *(u32*)(xr)       = pack2bf(mex, mey);
  *(u32*)(xr + 128) = pack2bf(mix, miy);
  *(u32*)(xr + 256) = pack2bf(max_, may_);
}

// ---------------- launch ----------------

extern "C" void kernel_launch(void* const* d_in, const int* in_sizes, int n_in,
                              void* d_out, int out_size, void* d_ws, size_t ws_size,
                              hipStream_t stream) {
  const float* x   = (const float*)d_in[0];
  const int*   src = (const int*)d_in[1];
  const int*   dst = (const int*)d_in[2];
  const float* Mw[3] = {(const float*)d_in[3], (const float*)d_in[7],  (const float*)d_in[11]};
  const float* Mb[3] = {(const float*)d_in[4], (const float*)d_in[8],  (const float*)d_in[12]};
  const float* Uw[3] = {(const float*)d_in[5], (const float*)d_in[9],  (const float*)d_in[13]};
  const float* Ub[3] = {(const float*)d_in[6], (const float*)d_in[10], (const float*)d_in[14]};
  float* out = (float*)d_out;

  char* ws = (char*)d_ws;
  size_t o = 0;
  auto alloc = [&](size_t bytes) -> char* {
    o = (o + 255) & ~(size_t)255;
    char* p = ws + o;
    o += bytes;
    return p;
  };
  int*   deg_i   = (int*)alloc((size_t)N_NODES * 4);
  int*   row_off = (int*)alloc((size_t)(N_NODES + 1) * 4);
  int*   excl    = (int*)alloc((size_t)N_NODES * 4);
  int*   bsum    = (int*)alloc((size_t)NB_SCAN * 4);
  int*   boff    = (int*)alloc((size_t)NB_SCAN * 4);
  int*   cursor  = (int*)alloc((size_t)N_NODES * 4);
  float* amp     = (float*)alloc((size_t)N_NODES * 4);
  float* att     = (float*)alloc((size_t)N_NODES * 4);
  int*   nbr     = (int*)alloc((size_t)N_EDGES * 4);
  u16*   Xh0     = (u16*)alloc((size_t)N_NODES * 512 * 2);   // 51.2 MB
  u16*   Xl0     = (u16*)alloc((size_t)N_NODES * 128 * 2);   // 12.8 MB
  u16*   Xh1     = (u16*)alloc((size_t)N_NODES * 512 * 2);   // 51.2 MB
  u16*   Xl1     = (u16*)alloc((size_t)N_NODES * 128 * 2);   // 12.8 MB
  u16*   ABa     = (u16*)alloc((size_t)N_NODES * 128 * 2);   // 12.8 MB
  float* ABb     = (float*)alloc((size_t)N_NODES * 128 * 4); // 25.6 MB
  u16*   WabTh[3]; u16* WabTl[3]; float* bias_ab[3];
  u16*   UTh[3];   u16* UTl[3];
  const int Nouts[3] = {128, 128, 64};
  for (int L = 0; L < 3; ++L) {
    WabTh[L] = (u16*)alloc((size_t)256 * 128 * 2);
    WabTl[L] = (u16*)alloc((size_t)256 * 128 * 2);
    bias_ab[L] = (float*)alloc(256 * 4);
    UTh[L] = (u16*)alloc((size_t)3 * Nouts[L] * 512 * 2);
    UTl[L] = (u16*)alloc((size_t)3 * Nouts[L] * 512 * 2);
  }

  // ---- graph structure ----
  hipMemsetAsync(deg_i, 0, (size_t)N_NODES * 4, stream);
  k_deg<<<(N_EDGES + 255) / 256, 256, 0, stream>>>(dst, deg_i);
  k_scan_local<<<NB_SCAN, 256, 0, stream>>>(deg_i, excl, bsum);
  k_scan_bsum<<<1, 256, 0, stream>>>(bsum, boff, row_off);
  k_scan_add<<<NB_SCAN, 256, 0, stream>>>(excl, boff, row_off);
  k_node_init<<<(N_NODES + 255) / 256, 256, 0, stream>>>(deg_i, row_off, cursor, amp, att);
  k_fill<<<(N_EDGES + 255) / 256, 256, 0, stream>>>(src, dst, cursor, nbr);

  // ---- weight prep + x pack ----
  for (int L = 0; L < 3; ++L) {
    k_prep_ab<<<256, 128, 0, stream>>>(Mw[L], Mb[L], WabTh[L], WabTl[L], bias_ab[L]);
    k_prep_u<<<dim3(2, Nouts[L], 3), 256, 0, stream>>>(Uw[L], UTh[L], UTl[L], Nouts[L]);
  }
  k_pack_x<<<(N_NODES * DIN + 255) / 256, 256, 0, stream>>>(x, Xh0, Xl0);

  const int MT = (N_NODES + 127) / 128;  // 391
  u16* XhIn[3] = {Xh0, Xh1, Xh0};
  u16* XlIn[3] = {Xl0, Xl1, Xl0};
  u16* XhOut[3] = {Xh1, Xh0, nullptr};
  u16* XlOut[3] = {Xl1, Xl0, nullptr};

  for (int L = 0; L < 3; ++L) {
    k_ab_gemm<<<dim3(MT, 2), 256, 0, stream>>>(XhIn[L], XlIn[L], WabTh[L], WabTl[L],
                                               bias_ab[L], ABa, ABb);
    k_agg<<<(N_NODES + 3) / 4, 256, 0, stream>>>(ABa, ABb, row_off, nbr, XhIn[L]);
    if (L < 2) {
      k_u_fused<128, 0><<<dim3(MT, 1), 256, 0, stream>>>(
          XhIn[L], XlIn[L], UTh[L], UTl[L], Ub[L], amp, att,
          XhOut[L], XlOut[L], nullptr, Nouts[L]);
    } else {
      k_u_fused<64, 1><<<dim3(MT, 1), 256, 0, stream>>>(
          XhIn[L], XlIn[L], UTh[L], UTl[L], Ub[L], amp, att,
          nullptr, nullptr, out, Nouts[L]);
    }
  }
}

// Round 7
// 680.360 us; speedup vs baseline: 1.4434x; 1.0245x over previous
//
#include <hip/hip_runtime.h>
#include <math.h>

#define N_NODES 50000
#define N_EDGES 800000
#define DIN 128
#define NB_SCAN ((N_NODES + 255) / 256)

typedef unsigned short u16;
typedef unsigned int u32;
typedef short short8 __attribute__((ext_vector_type(8)));
typedef float f32x4 __attribute__((ext_vector_type(4)));

__device__ __forceinline__ u16 f2bf(float x) {
  u32 u = __float_as_uint(x);
  u32 r = (u + 0x7FFFu + ((u >> 16) & 1u)) >> 16;
  return (u16)r;
}
__device__ __forceinline__ float bf2f(u16 h) { return __uint_as_float(((u32)h) << 16); }
__device__ __forceinline__ u32 pack2bf(float x, float y) {
  return (u32)f2bf(x) | ((u32)f2bf(y) << 16);
}

__device__ __forceinline__ f32x4 mfma_bf16(short8 a, short8 b, f32x4 c) {
  return __builtin_amdgcn_mfma_f32_16x16x32_bf16(a, b, c, 0, 0, 0);
}

// swizzled BYTE offset within a [rows][64 bf16] LDS tile (128B rows)
#define SWZ(row, byt) ((row) * 128 + ((byt) ^ (((row) & 7) << 4)))

// ---------------- graph setup ----------------

__global__ void k_deg(const int* __restrict__ dst, int* __restrict__ deg) {
  int e = blockIdx.x * blockDim.x + threadIdx.x;
  if (e < N_EDGES) atomicAdd(&deg[dst[e]], 1);
}

__global__ void k_scan_local(const int* __restrict__ deg, int* __restrict__ excl,
                             int* __restrict__ bsum) {
  __shared__ int sm[256];
  int tid = threadIdx.x;
  int i = blockIdx.x * 256 + tid;
  int v = (i < N_NODES) ? deg[i] : 0;
  sm[tid] = v;
  __syncthreads();
  for (int off = 1; off < 256; off <<= 1) {
    int t = (tid >= off) ? sm[tid - off] : 0;
    __syncthreads();
    sm[tid] += t;
    __syncthreads();
  }
  if (i < N_NODES) excl[i] = sm[tid] - v;
  if (tid == 255) bsum[blockIdx.x] = sm[255];
}

__global__ void k_scan_bsum(const int* __restrict__ bsum, int* __restrict__ boff,
                            int* __restrict__ row_off) {
  __shared__ int sm[256];
  int tid = threadIdx.x;
  int v = (tid < NB_SCAN) ? bsum[tid] : 0;
  sm[tid] = v;
  __syncthreads();
  for (int off = 1; off < 256; off <<= 1) {
    int t = (tid >= off) ? sm[tid - off] : 0;
    __syncthreads();
    sm[tid] += t;
    __syncthreads();
  }
  if (tid < NB_SCAN) boff[tid] = sm[tid] - v;
  if (tid == 255) row_off[N_NODES] = sm[255];
}

__global__ void k_scan_add(const int* __restrict__ excl, const int* __restrict__ boff,
                           int* __restrict__ row_off) {
  int i = blockIdx.x * 256 + threadIdx.x;
  if (i < N_NODES) row_off[i] = excl[i] + boff[i >> 8];
}

__global__ void k_node_init(const int* __restrict__ deg, const int* __restrict__ row_off,
                            int* __restrict__ cursor, float* __restrict__ amp,
                            float* __restrict__ att) {
  int v = blockIdx.x * blockDim.x + threadIdx.x;
  if (v >= N_NODES) return;
  cursor[v] = row_off[v];
  float d = (float)deg[v];
  float logd = logf(d + 1.0f);
  amp[v] = logd / 3.0f;
  att[v] = 3.0f / fmaxf(logd, 1e-6f);
}

__global__ void k_fill(const int* __restrict__ src, const int* __restrict__ dst,
                       int* __restrict__ cursor, int* __restrict__ nbr) {
  int e = blockIdx.x * blockDim.x + threadIdx.x;
  if (e >= N_EDGES) return;
  int slot = atomicAdd(&cursor[dst[e]], 1);
  nbr[slot] = src[e];
}

// ---------------- weight prep ----------------

// WabT[j][k] = j<128 ? Mw[k][j] : Mw[128+k][j-128]   ([256][128] hi/lo)
__global__ void k_prep_ab(const float* __restrict__ Mw, const float* __restrict__ Mb,
                          u16* __restrict__ Th, u16* __restrict__ Tl,
                          float* __restrict__ bias_ab) {
  int j = blockIdx.x;     // 0..255
  int k = threadIdx.x;    // 0..127
  float w = (j < 128) ? Mw[k * 128 + j] : Mw[(128 + k) * 128 + (j - 128)];
  u16 hi = f2bf(w);
  u16 lo = f2bf(w - bf2f(hi));
  Th[j * 128 + k] = hi;
  Tl[j * 128 + k] = lo;
  if (k == 0) bias_ab[j] = (j < 128) ? 0.f : Mb[j - 128];
}

// UT[p][j][k], k in [0,512): p==0 -> Uw rows 0..511; p>0, k>=128 -> Uw rows 512+384*(p-1)+(k-128)
__global__ void k_prep_u(const float* __restrict__ Uw, u16* __restrict__ Th,
                         u16* __restrict__ Tl, int Nout) {
  int k = blockIdx.x * 256 + threadIdx.x;  // 0..511
  int j = blockIdx.y;
  int p = blockIdx.z;
  if (p > 0 && k < 128) return;
  int srow = (p == 0) ? k : 512 + 384 * (p - 1) + (k - 128);
  float w = Uw[(size_t)srow * Nout + j];
  u16 hi = f2bf(w);
  u16 lo = f2bf(w - bf2f(hi));
  size_t idx = ((size_t)p * Nout + j) * 512 + k;
  Th[idx] = hi;
  Tl[idx] = lo;
}

// ---------------- layer-0 x pack: Xh (hi, stride 512) + Xl (lo, stride 128) ----------------

__global__ void k_pack_x(const float* __restrict__ x, u16* __restrict__ Xh,
                         u16* __restrict__ Xl) {
  int i = blockIdx.x * 256 + threadIdx.x;
  if (i >= N_NODES * DIN) return;
  int g = i >> 7, c = i & 127;
  float v = x[i];
  u16 hi = f2bf(v);
  Xh[(size_t)g * 512 + c] = hi;
  Xl[(size_t)g * 128 + c] = f2bf(v - bf2f(hi));
}

// ---------------- AB GEMM: [N][256] = h @ [Mw_top | Mw_bot], BM=128 BN=64 ----------------

__global__ __launch_bounds__(256, 3) void k_ab_gemm(
    const u16* __restrict__ Xh, const u16* __restrict__ Xl,
    const u16* __restrict__ WTh, const u16* __restrict__ WTl,
    const float* __restrict__ bias, u16* __restrict__ ABa, float* __restrict__ ABb) {
  __shared__ __align__(16) u16 Ah[128 * 64];
  __shared__ __align__(16) u16 Al[128 * 64];
  __shared__ __align__(16) u16 Bh[64 * 64];
  __shared__ __align__(16) u16 Bl[64 * 64];

  const int tid = threadIdx.x;
  const int row0 = blockIdx.x * 128;
  const int col0 = blockIdx.y * 64;
  const int lane = tid & 63;
  const int wave = tid >> 6;
  const int wrow = (wave >> 1) * 64;
  const int wcol = (wave & 1) * 32;

  f32x4 acc[4][2];
  const f32x4 zero4 = {0.f, 0.f, 0.f, 0.f};
#pragma unroll
  for (int i = 0; i < 4; ++i)
#pragma unroll
    for (int n = 0; n < 2; ++n) acc[i][n] = zero4;

  for (int k0 = 0; k0 < 128; k0 += 64) {
    __syncthreads();
#pragma unroll
    for (int r = 0; r < 4; ++r) {  // A: 128 rows x 8 chunks(16B)
      int op = r * 256 + tid;
      int m = op >> 3, ch = op & 7;
      int g = row0 + m;
      uint4 hv = {0u, 0u, 0u, 0u}, lv = {0u, 0u, 0u, 0u};
      if (g < N_NODES) {
        hv = *(const uint4*)(Xh + (size_t)g * 512 + k0 + ch * 8);
        lv = *(const uint4*)(Xl + (size_t)g * 128 + k0 + ch * 8);
      }
      int ad = SWZ(m, ch * 16);
      *(uint4*)((char*)Ah + ad) = hv;
      *(uint4*)((char*)Al + ad) = lv;
    }
#pragma unroll
    for (int r = 0; r < 2; ++r) {  // B: 64 cols x 8 chunks
      int op = r * 256 + tid;
      int c = op >> 3, sl = op & 7;
      int bd = SWZ(c, sl * 16);
      *(uint4*)((char*)Bh + bd) = *(const uint4*)(WTh + (size_t)(col0 + c) * 128 + k0 + sl * 8);
      *(uint4*)((char*)Bl + bd) = *(const uint4*)(WTl + (size_t)(col0 + c) * 128 + k0 + sl * 8);
    }
    __syncthreads();
#pragma unroll
    for (int kk = 0; kk < 2; ++kk) {
      const int kb = kk * 64 + (lane >> 4) * 16;
      short8 a_h[4], a_l[4];
#pragma unroll
      for (int i = 0; i < 4; ++i) {
        int rr = wrow + i * 16 + (lane & 15);
        a_h[i] = *(const short8*)((const char*)Ah + SWZ(rr, kb));
        a_l[i] = *(const short8*)((const char*)Al + SWZ(rr, kb));
      }
#pragma unroll
      for (int n = 0; n < 2; ++n) {
        int cc = wcol + n * 16 + (lane & 15);
        short8 b_h = *(const short8*)((const char*)Bh + SWZ(cc, kb));
        short8 b_l = *(const short8*)((const char*)Bl + SWZ(cc, kb));
#pragma unroll
        for (int i = 0; i < 4; ++i) {
          acc[i][n] = mfma_bf16(a_h[i], b_h, acc[i][n]);
          acc[i][n] = mfma_bf16(a_h[i], b_l, acc[i][n]);
          acc[i][n] = mfma_bf16(a_l[i], b_h, acc[i][n]);
        }
      }
    }
  }
#pragma unroll
  for (int i = 0; i < 4; ++i) {
#pragma unroll
    for (int n = 0; n < 2; ++n) {
      int gr0 = row0 + wrow + i * 16 + (lane >> 4) * 4;
      int gc = col0 + wcol + n * 16 + (lane & 15);
#pragma unroll
      for (int q = 0; q < 4; ++q) {
        int gr = gr0 + q;
        if (gr >= N_NODES) continue;
        float v = acc[i][n][q];
        if (gc < 128) ABa[(size_t)gr * 128 + gc] = f2bf(v);
        else ABb[(size_t)gr * 128 + (gc - 128)] = v + bias[gc];
      }
    }
  }
}

// ---------------- fused U GEMM: loop1 = plane0 (k 0..512), loop2 = planes1+2 (k 128..512, A staged once) ----------------

template <int BN, int LAST>
__global__ __launch_bounds__(256, 3) void k_u_fused(
    const u16* __restrict__ Xh, const u16* __restrict__ Xl,
    const u16* __restrict__ UTh, const u16* __restrict__ UTl,
    const float* __restrict__ Ub, const float* __restrict__ amp,
    const float* __restrict__ att, u16* __restrict__ XhW, u16* __restrict__ XlW,
    float* __restrict__ outF, int Nout) {
  constexpr int NREP = BN / 32;
  constexpr int BE = BN * 64;                     // elems per B array
  constexpr int L1E = 16384 + 2 * BE;             // loop1 footprint
  constexpr int L2E = 8192 + 4 * BE;              // loop2 footprint
  constexpr int LDSE = (L1E > L2E) ? L1E : L2E;
  __shared__ __align__(16) u16 LDS[LDSE];
  u16* Ah  = LDS;                 // [128][64]
  u16* Al  = LDS + 8192;          // loop1 (h steps) only
  u16* B0h = LDS + 16384;         // loop1
  u16* B0l = LDS + 16384 + BE;
  u16* B1h = LDS + 8192;          // loop2 aliases
  u16* B1l = LDS + 8192 + BE;
  u16* B2h = LDS + 8192 + 2 * BE;
  u16* B2l = LDS + 8192 + 3 * BE;

  const int tid = threadIdx.x;
  const int row0 = blockIdx.x * 128;
  const int col0 = blockIdx.y * BN;
  const int lane = tid & 63;
  const int wave = tid >> 6;
  const int wrow = (wave >> 1) * 64;
  const int wcol = (wave & 1) * (BN / 2);

  const u16* U0h = UTh + (size_t)col0 * 512;
  const u16* U0l = UTl + (size_t)col0 * 512;
  const u16* U1h = UTh + (size_t)(Nout + col0) * 512;
  const u16* U1l = UTl + (size_t)(Nout + col0) * 512;
  const u16* U2h = UTh + (size_t)(2 * Nout + col0) * 512;
  const u16* U2l = UTl + (size_t)(2 * Nout + col0) * 512;

  f32x4 acc_t[4][NREP], acc_p1[4][NREP], acc_p2[4][NREP];
  const f32x4 zero4 = {0.f, 0.f, 0.f, 0.f};
#pragma unroll
  for (int i = 0; i < 4; ++i)
#pragma unroll
    for (int n = 0; n < NREP; ++n) {
      acc_t[i][n] = zero4; acc_p1[i][n] = zero4; acc_p2[i][n] = zero4;
    }

  // ---- loop1: plane 0 over k=0..512 (h part 3-prod, agg part 2-prod) ----
  for (int k0 = 0; k0 < 512; k0 += 64) {
    const bool hstep = (k0 < 128);
    __syncthreads();
#pragma unroll
    for (int r = 0; r < 4; ++r) {
      int op = r * 256 + tid;
      int m = op >> 3, ch = op & 7;
      int g = row0 + m;
      int ad = SWZ(m, ch * 16);
      uint4 hv = {0u, 0u, 0u, 0u};
      if (g < N_NODES) hv = *(const uint4*)(Xh + (size_t)g * 512 + k0 + ch * 8);
      *(uint4*)((char*)Ah + ad) = hv;
      if (hstep) {
        uint4 lv = {0u, 0u, 0u, 0u};
        if (g < N_NODES) lv = *(const uint4*)(Xl + (size_t)g * 128 + k0 + ch * 8);
        *(uint4*)((char*)Al + ad) = lv;
      }
    }
#pragma unroll
    for (int r = 0; r < NREP; ++r) {
      int op = r * 256 + tid;
      int c = op >> 3, sl = op & 7;
      int bd = SWZ(c, sl * 16);
      *(uint4*)((char*)B0h + bd) = *(const uint4*)(U0h + (size_t)c * 512 + k0 + sl * 8);
      *(uint4*)((char*)B0l + bd) = *(const uint4*)(U0l + (size_t)c * 512 + k0 + sl * 8);
    }
    __syncthreads();
#pragma unroll
    for (int kk = 0; kk < 2; ++kk) {
      const int kb = kk * 64 + (lane >> 4) * 16;
      short8 a_h[4], a_l[4];
#pragma unroll
      for (int i = 0; i < 4; ++i) {
        int rr = wrow + i * 16 + (lane & 15);
        a_h[i] = *(const short8*)((const char*)Ah + SWZ(rr, kb));
        if (hstep) a_l[i] = *(const short8*)((const char*)Al + SWZ(rr, kb));
      }
#pragma unroll
      for (int n = 0; n < NREP; ++n) {
        int cc = wcol + n * 16 + (lane & 15);
        short8 b_h = *(const short8*)((const char*)B0h + SWZ(cc, kb));
        short8 b_l = *(const short8*)((const char*)B0l + SWZ(cc, kb));
#pragma unroll
        for (int i = 0; i < 4; ++i) {
          acc_t[i][n] = mfma_bf16(a_h[i], b_h, acc_t[i][n]);
          acc_t[i][n] = mfma_bf16(a_h[i], b_l, acc_t[i][n]);
          if (hstep) acc_t[i][n] = mfma_bf16(a_l[i], b_h, acc_t[i][n]);
        }
      }
    }
  }

  // ---- loop2: planes 1+2 over k=128..512, A-hi staged ONCE per k-step ----
  for (int k0 = 128; k0 < 512; k0 += 64) {
    __syncthreads();
#pragma unroll
    for (int r = 0; r < 4; ++r) {
      int op = r * 256 + tid;
      int m = op >> 3, ch = op & 7;
      int g = row0 + m;
      uint4 hv = {0u, 0u, 0u, 0u};
      if (g < N_NODES) hv = *(const uint4*)(Xh + (size_t)g * 512 + k0 + ch * 8);
      *(uint4*)((char*)Ah + SWZ(m, ch * 16)) = hv;
    }
#pragma unroll
    for (int r = 0; r < NREP; ++r) {
      int op = r * 256 + tid;
      int c = op >> 3, sl = op & 7;
      int bd = SWZ(c, sl * 16);
      *(uint4*)((char*)B1h + bd) = *(const uint4*)(U1h + (size_t)c * 512 + k0 + sl * 8);
      *(uint4*)((char*)B1l + bd) = *(const uint4*)(U1l + (size_t)c * 512 + k0 + sl * 8);
      *(uint4*)((char*)B2h + bd) = *(const uint4*)(U2h + (size_t)c * 512 + k0 + sl * 8);
      *(uint4*)((char*)B2l + bd) = *(const uint4*)(U2l + (size_t)c * 512 + k0 + sl * 8);
    }
    __syncthreads();
#pragma unroll
    for (int kk = 0; kk < 2; ++kk) {
      const int kb = kk * 64 + (lane >> 4) * 16;
      short8 a_h[4];
#pragma unroll
      for (int i = 0; i < 4; ++i) {
        int rr = wrow + i * 16 + (lane & 15);
        a_h[i] = *(const short8*)((const char*)Ah + SWZ(rr, kb));
      }
#pragma unroll
      for (int n = 0; n < NREP; ++n) {
        int cc = wcol + n * 16 + (lane & 15);
        short8 b1h = *(const short8*)((const char*)B1h + SWZ(cc, kb));
        short8 b1l = *(const short8*)((const char*)B1l + SWZ(cc, kb));
        short8 b2h = *(const short8*)((const char*)B2h + SWZ(cc, kb));
        short8 b2l = *(const short8*)((const char*)B2l + SWZ(cc, kb));
#pragma unroll
        for (int i = 0; i < 4; ++i) {
          acc_p1[i][n] = mfma_bf16(a_h[i], b1h, acc_p1[i][n]);
          acc_p1[i][n] = mfma_bf16(a_h[i], b1l, acc_p1[i][n]);
          acc_p2[i][n] = mfma_bf16(a_h[i], b2h, acc_p2[i][n]);
          acc_p2[i][n] = mfma_bf16(a_h[i], b2l, acc_p2[i][n]);
        }
      }
    }
  }

  // ---- merge + epilogue ----
#pragma unroll
  for (int i = 0; i < 4; ++i) {
    int gr0 = row0 + wrow + i * 16 + (lane >> 4) * 4;
    f32x4 a1 = *(const f32x4*)(amp + gr0);
    f32x4 a2 = *(const f32x4*)(att + gr0);
#pragma unroll
    for (int n = 0; n < NREP; ++n) {
      int gc = col0 + wcol + n * 16 + (lane & 15);
      float b = Ub[gc];
#pragma unroll
      for (int q = 0; q < 4; ++q) {
        int gr = gr0 + q;
        if (gr >= N_NODES) continue;
        float v = acc_t[i][n][q] + a1[q] * acc_p1[i][n][q] + a2[q] * acc_p2[i][n][q] + b;
        if (LAST) {
          outF[(size_t)gr * 64 + gc] = v;
        } else {
          float t = fmaxf(v, 0.f);
          u16 hi = f2bf(t);
          XhW[(size_t)gr * 512 + gc] = hi;
          XlW[(size_t)gr * 128 + gc] = f2bf(t - bf2f(hi));
        }
      }
    }
  }
}

// ---------------- aggregation: one wave/node. Reads ABa/ABb, WRITES XhDst cols 128..511 ----------------

__global__ __launch_bounds__(256) void k_agg(const u16* __restrict__ ABa,
                                             const float* __restrict__ ABb,
                                             const int* __restrict__ row_off,
                                             const int* __restrict__ nbr,
                                             u16* __restrict__ XhDst) {
  int v = blockIdx.x * 4 + (threadIdx.x >> 6);
  int lane = threadIdx.x & 63;
  if (v >= N_NODES) return;
  int beg = row_off[v], end = row_off[v + 1];
  const u32* A32 = (const u32*)ABa;  // [N][64] u32 (2 bf16 each)
  float sx = 0.f, sy = 0.f;
  float mnx = 3.4e38f, mny = 3.4e38f;
  float mxx = -3.4e38f, mxy = -3.4e38f;
  int i = beg;
#define ACC(w)                                              \
  {                                                         \
    float ax = bf2f((u16)(w)), ay = bf2f((u16)((w) >> 16)); \
    sx += ax; sy += ay;                                     \
    mnx = fminf(mnx, ax); mny = fminf(mny, ay);             \
    mxx = fmaxf(mxx, ax); mxy = fmaxf(mxy, ay);             \
  }
  for (; i + 4 <= end; i += 4) {
    int s0 = nbr[i], s1 = nbr[i + 1], s2 = nbr[i + 2], s3 = nbr[i + 3];
    u32 w0 = A32[(size_t)s0 * 64 + lane];
    u32 w1 = A32[(size_t)s1 * 64 + lane];
    u32 w2 = A32[(size_t)s2 * 64 + lane];
    u32 w3 = A32[(size_t)s3 * 64 + lane];
    ACC(w0) ACC(w1) ACC(w2) ACC(w3)
  }
  for (; i < end; ++i) {
    u32 w = A32[(size_t)nbr[i] * 64 + lane];
    ACC(w)
  }
#undef ACC
  int d = end - beg;
  int c = lane * 2;
  float2 b = *(const float2*)&ABb[(size_t)v * 128 + c];
  float mex, mey, mix, miy, max_, may_;
  if (d > 0) {
    float inv = 1.f / (float)d;
    mex = sx * inv + b.x; mey = sy * inv + b.y;
    mix = mnx + b.x; miy = mny + b.y;
    max_ = mxx + b.x; may_ = mxy + b.y;
  } else {
    mex = mey = mix = miy = max_ = may_ = 0.f;
  }
  u16* xr = XhDst + (size_t)v * 512 + 128 + c;
  *(u32*)(xr)       = pack2bf(mex, mey);
  *(u32*)(xr + 128) = pack2bf(mix, miy);
  *(u32*)(xr + 256) = pack2bf(max_, may_);
}

// ---------------- launch ----------------

extern "C" void kernel_launch(void* const* d_in, const int* in_sizes, int n_in,
                              void* d_out, int out_size, void* d_ws, size_t ws_size,
                              hipStream_t stream) {
  const float* x   = (const float*)d_in[0];
  const int*   src = (const int*)d_in[1];
  const int*   dst = (const int*)d_in[2];
  const float* Mw[3] = {(const float*)d_in[3], (const float*)d_in[7],  (const float*)d_in[11]};
  const float* Mb[3] = {(const float*)d_in[4], (const float*)d_in[8],  (const float*)d_in[12]};
  const float* Uw[3] = {(const float*)d_in[5], (const float*)d_in[9],  (const float*)d_in[13]};
  const float* Ub[3] = {(const float*)d_in[6], (const float*)d_in[10], (const float*)d_in[14]};
  float* out = (float*)d_out;

  char* ws = (char*)d_ws;
  size_t o = 0;
  auto alloc = [&](size_t bytes) -> char* {
    o = (o + 255) & ~(size_t)255;
    char* p = ws + o;
    o += bytes;
    return p;
  };
  int*   deg_i   = (int*)alloc((size_t)N_NODES * 4);
  int*   row_off = (int*)alloc((size_t)(N_NODES + 1) * 4);
  int*   excl    = (int*)alloc((size_t)N_NODES * 4);
  int*   bsum    = (int*)alloc((size_t)NB_SCAN * 4);
  int*   boff    = (int*)alloc((size_t)NB_SCAN * 4);
  int*   cursor  = (int*)alloc((size_t)N_NODES * 4);
  float* amp     = (float*)alloc((size_t)N_NODES * 4);
  float* att     = (float*)alloc((size_t)N_NODES * 4);
  int*   nbr     = (int*)alloc((size_t)N_EDGES * 4);
  u16*   Xh0     = (u16*)alloc((size_t)N_NODES * 512 * 2);   // 51.2 MB
  u16*   Xl0     = (u16*)alloc((size_t)N_NODES * 128 * 2);   // 12.8 MB
  u16*   Xh1     = (u16*)alloc((size_t)N_NODES * 512 * 2);   // 51.2 MB
  u16*   Xl1     = (u16*)alloc((size_t)N_NODES * 128 * 2);   // 12.8 MB
  u16*   ABa     = (u16*)alloc((size_t)N_NODES * 128 * 2);   // 12.8 MB
  float* ABb     = (float*)alloc((size_t)N_NODES * 128 * 4); // 25.6 MB
  u16*   WabTh[3]; u16* WabTl[3]; float* bias_ab[3];
  u16*   UTh[3];   u16* UTl[3];
  const int Nouts[3] = {128, 128, 64};
  for (int L = 0; L < 3; ++L) {
    WabTh[L] = (u16*)alloc((size_t)256 * 128 * 2);
    WabTl[L] = (u16*)alloc((size_t)256 * 128 * 2);
    bias_ab[L] = (float*)alloc(256 * 4);
    UTh[L] = (u16*)alloc((size_t)3 * Nouts[L] * 512 * 2);
    UTl[L] = (u16*)alloc((size_t)3 * Nouts[L] * 512 * 2);
  }

  // ---- graph structure ----
  hipMemsetAsync(deg_i, 0, (size_t)N_NODES * 4, stream);
  k_deg<<<(N_EDGES + 255) / 256, 256, 0, stream>>>(dst, deg_i);
  k_scan_local<<<NB_SCAN, 256, 0, stream>>>(deg_i, excl, bsum);
  k_scan_bsum<<<1, 256, 0, stream>>>(bsum, boff, row_off);
  k_scan_add<<<NB_SCAN, 256, 0, stream>>>(excl, boff, row_off);
  k_node_init<<<(N_NODES + 255) / 256, 256, 0, stream>>>(deg_i, row_off, cursor, amp, att);
  k_fill<<<(N_EDGES + 255) / 256, 256, 0, stream>>>(src, dst, cursor, nbr);

  // ---- weight prep + x pack ----
  for (int L = 0; L < 3; ++L) {
    k_prep_ab<<<256, 128, 0, stream>>>(Mw[L], Mb[L], WabTh[L], WabTl[L], bias_ab[L]);
    k_prep_u<<<dim3(2, Nouts[L], 3), 256, 0, stream>>>(Uw[L], UTh[L], UTl[L], Nouts[L]);
  }
  k_pack_x<<<(N_NODES * DIN + 255) / 256, 256, 0, stream>>>(x, Xh0, Xl0);

  const int MT = (N_NODES + 127) / 128;  // 391
  u16* XhIn[3] = {Xh0, Xh1, Xh0};
  u16* XlIn[3] = {Xl0, Xl1, Xl0};
  u16* XhOut[3] = {Xh1, Xh0, nullptr};
  u16* XlOut[3] = {Xl1, Xl0, nullptr};

  for (int L = 0; L < 3; ++L) {
    k_ab_gemm<<<dim3(MT, 4), 256, 0, stream>>>(XhIn[L], XlIn[L], WabTh[L], WabTl[L],
                                               bias_ab[L], ABa, ABb);
    k_agg<<<(N_NODES + 3) / 4, 256, 0, stream>>>(ABa, ABb, row_off, nbr, XhIn[L]);
    if (L < 2) {
      k_u_fused<64, 0><<<dim3(MT, 2), 256, 0, stream>>>(
          XhIn[L], XlIn[L], UTh[L], UTl[L], Ub[L], amp, att,
          XhOut[L], XlOut[L], nullptr, Nouts[L]);
    } else {
      k_u_fused<32, 1><<<dim3(MT, 2), 256, 0, stream>>>(
          XhIn[L], XlIn[L], UTh[L], UTl[L], Ub[L], amp, att,
          nullptr, nullptr, out, Nouts[L]);
    }
  }
}

// Round 8
// 601.185 us; speedup vs baseline: 1.6335x; 1.1317x over previous
//
#include <hip/hip_runtime.h>
#include <math.h>

#define N_NODES 50000
#define N_EDGES 800000
#define DIN 128
#define NB_SCAN ((N_NODES + 255) / 256)

typedef unsigned short u16;
typedef unsigned int u32;
typedef short short8 __attribute__((ext_vector_type(8)));
typedef float f32x4 __attribute__((ext_vector_type(4)));

__device__ __forceinline__ u16 f2bf(float x) {
  u32 u = __float_as_uint(x);
  u32 r = (u + 0x7FFFu + ((u >> 16) & 1u)) >> 16;
  return (u16)r;
}
__device__ __forceinline__ float bf2f(u16 h) { return __uint_as_float(((u32)h) << 16); }
__device__ __forceinline__ u32 pack2bf(float x, float y) {
  return (u32)f2bf(x) | ((u32)f2bf(y) << 16);
}

__device__ __forceinline__ f32x4 mfma_bf16(short8 a, short8 b, f32x4 c) {
  return __builtin_amdgcn_mfma_f32_16x16x32_bf16(a, b, c, 0, 0, 0);
}

// async global->LDS, 16B per lane. LDS dest must be linear (wave base + lane*16).
__device__ __forceinline__ void g2l16(const void* g, void* l) {
  __builtin_amdgcn_global_load_lds(
      (const __attribute__((address_space(1))) u32*)g,
      (__attribute__((address_space(3))) u32*)l, 16, 0, 0);
}

// swizzled BYTE offset within a [rows][64 bf16] LDS tile (128B rows) — READ side
#define SWZ(row, byt) ((row) * 128 + ((byt) ^ (((row) & 7) << 4)))

// ---------------- graph setup ----------------

__global__ void k_deg(const int* __restrict__ dst, int* __restrict__ deg) {
  int e = blockIdx.x * blockDim.x + threadIdx.x;
  if (e < N_EDGES) atomicAdd(&deg[dst[e]], 1);
}

__global__ void k_scan_local(const int* __restrict__ deg, int* __restrict__ excl,
                             int* __restrict__ bsum) {
  __shared__ int sm[256];
  int tid = threadIdx.x;
  int i = blockIdx.x * 256 + tid;
  int v = (i < N_NODES) ? deg[i] : 0;
  sm[tid] = v;
  __syncthreads();
  for (int off = 1; off < 256; off <<= 1) {
    int t = (tid >= off) ? sm[tid - off] : 0;
    __syncthreads();
    sm[tid] += t;
    __syncthreads();
  }
  if (i < N_NODES) excl[i] = sm[tid] - v;
  if (tid == 255) bsum[blockIdx.x] = sm[255];
}

__global__ void k_scan_bsum(const int* __restrict__ bsum, int* __restrict__ boff,
                            int* __restrict__ row_off) {
  __shared__ int sm[256];
  int tid = threadIdx.x;
  int v = (tid < NB_SCAN) ? bsum[tid] : 0;
  sm[tid] = v;
  __syncthreads();
  for (int off = 1; off < 256; off <<= 1) {
    int t = (tid >= off) ? sm[tid - off] : 0;
    __syncthreads();
    sm[tid] += t;
    __syncthreads();
  }
  if (tid < NB_SCAN) boff[tid] = sm[tid] - v;
  if (tid == 255) row_off[N_NODES] = sm[255];
}

__global__ void k_scan_add(const int* __restrict__ excl, const int* __restrict__ boff,
                           int* __restrict__ row_off) {
  int i = blockIdx.x * 256 + threadIdx.x;
  if (i < N_NODES) row_off[i] = excl[i] + boff[i >> 8];
}

__global__ void k_node_init(const int* __restrict__ deg, const int* __restrict__ row_off,
                            int* __restrict__ cursor, float* __restrict__ amp,
                            float* __restrict__ att) {
  int v = blockIdx.x * blockDim.x + threadIdx.x;
  if (v >= N_NODES) return;
  cursor[v] = row_off[v];
  float d = (float)deg[v];
  float logd = logf(d + 1.0f);
  amp[v] = logd / 3.0f;
  att[v] = 3.0f / fmaxf(logd, 1e-6f);
}

__global__ void k_fill(const int* __restrict__ src, const int* __restrict__ dst,
                       int* __restrict__ cursor, int* __restrict__ nbr) {
  int e = blockIdx.x * blockDim.x + threadIdx.x;
  if (e >= N_EDGES) return;
  int slot = atomicAdd(&cursor[dst[e]], 1);
  nbr[slot] = src[e];
}

// ---------------- weight prep ----------------

// WabT[j][k] = j<128 ? Mw[k][j] : Mw[128+k][j-128]   ([256][128] hi/lo)
__global__ void k_prep_ab(const float* __restrict__ Mw, const float* __restrict__ Mb,
                          u16* __restrict__ Th, u16* __restrict__ Tl,
                          float* __restrict__ bias_ab) {
  int j = blockIdx.x;     // 0..255
  int k = threadIdx.x;    // 0..127
  float w = (j < 128) ? Mw[k * 128 + j] : Mw[(128 + k) * 128 + (j - 128)];
  u16 hi = f2bf(w);
  u16 lo = f2bf(w - bf2f(hi));
  Th[j * 128 + k] = hi;
  Tl[j * 128 + k] = lo;
  if (k == 0) bias_ab[j] = (j < 128) ? 0.f : Mb[j - 128];
}

// UT[p][j][k], k in [0,512): p==0 -> Uw rows 0..511; p>0, k>=128 -> Uw rows 512+384*(p-1)+(k-128)
__global__ void k_prep_u(const float* __restrict__ Uw, u16* __restrict__ Th,
                         u16* __restrict__ Tl, int Nout) {
  int k = blockIdx.x * 256 + threadIdx.x;  // 0..511
  int j = blockIdx.y;
  int p = blockIdx.z;
  if (p > 0 && k < 128) return;
  int srow = (p == 0) ? k : 512 + 384 * (p - 1) + (k - 128);
  float w = Uw[(size_t)srow * Nout + j];
  u16 hi = f2bf(w);
  u16 lo = f2bf(w - bf2f(hi));
  size_t idx = ((size_t)p * Nout + j) * 512 + k;
  Th[idx] = hi;
  Tl[idx] = lo;
}

// ---------------- layer-0 x pack: Xh (hi, stride 512) + Xl (lo, stride 128) ----------------

__global__ void k_pack_x(const float* __restrict__ x, u16* __restrict__ Xh,
                         u16* __restrict__ Xl) {
  int i = blockIdx.x * 256 + threadIdx.x;
  if (i >= N_NODES * DIN) return;
  int g = i >> 7, c = i & 127;
  float v = x[i];
  u16 hi = f2bf(v);
  Xh[(size_t)g * 512 + c] = hi;
  Xl[(size_t)g * 128 + c] = f2bf(v - bf2f(hi));
}

// ---------------- AB GEMM: [N][256] = h @ [Mw_top | Mw_bot], BM=128 BN=64 ----------------
// Staging: global_load_lds w=16, linear LDS dest + pre-swizzled global source (rule #21).

__global__ __launch_bounds__(256, 3) void k_ab_gemm(
    const u16* __restrict__ Xh, const u16* __restrict__ Xl,
    const u16* __restrict__ WTh, const u16* __restrict__ WTl,
    const float* __restrict__ bias, u16* __restrict__ ABa, float* __restrict__ ABb) {
  __shared__ __align__(16) u16 Ah[128 * 64];
  __shared__ __align__(16) u16 Al[128 * 64];
  __shared__ __align__(16) u16 Bh[64 * 64];
  __shared__ __align__(16) u16 Bl[64 * 64];

  const int tid = threadIdx.x;
  const int row0 = blockIdx.x * 128;
  const int col0 = blockIdx.y * 64;
  const int lane = tid & 63;
  const int wave = tid >> 6;
  const int wrow = (wave >> 1) * 64;
  const int wcol = (wave & 1) * 32;

  f32x4 acc[4][2];
  const f32x4 zero4 = {0.f, 0.f, 0.f, 0.f};
#pragma unroll
  for (int i = 0; i < 4; ++i)
#pragma unroll
    for (int n = 0; n < 2; ++n) acc[i][n] = zero4;

  for (int k0 = 0; k0 < 128; k0 += 64) {
    __syncthreads();
#pragma unroll
    for (int r = 0; r < 4; ++r) {  // A: 128 rows x 8 chunks(16B)
      int op = r * 256 + tid;
      int m = op >> 3, ch = op & 7;
      int chx = ch ^ (m & 7);                 // pre-swizzled source chunk
      int g = row0 + m;
      if (g >= N_NODES) g = N_NODES - 1;      // clamp: junk rows never stored
      g2l16(Xh + (size_t)g * 512 + k0 + chx * 8, (char*)Ah + op * 16);
      g2l16(Xl + (size_t)g * 128 + k0 + chx * 8, (char*)Al + op * 16);
    }
#pragma unroll
    for (int r = 0; r < 2; ++r) {  // B: 64 cols x 8 chunks
      int op = r * 256 + tid;
      int c = op >> 3, sl = op & 7;
      int slx = sl ^ (c & 7);
      g2l16(WTh + (size_t)(col0 + c) * 128 + k0 + slx * 8, (char*)Bh + op * 16);
      g2l16(WTl + (size_t)(col0 + c) * 128 + k0 + slx * 8, (char*)Bl + op * 16);
    }
    __syncthreads();
#pragma unroll
    for (int kk = 0; kk < 2; ++kk) {
      const int kb = kk * 64 + (lane >> 4) * 16;
      short8 a_h[4], a_l[4];
#pragma unroll
      for (int i = 0; i < 4; ++i) {
        int rr = wrow + i * 16 + (lane & 15);
        a_h[i] = *(const short8*)((const char*)Ah + SWZ(rr, kb));
        a_l[i] = *(const short8*)((const char*)Al + SWZ(rr, kb));
      }
#pragma unroll
      for (int n = 0; n < 2; ++n) {
        int cc = wcol + n * 16 + (lane & 15);
        short8 b_h = *(const short8*)((const char*)Bh + SWZ(cc, kb));
        short8 b_l = *(const short8*)((const char*)Bl + SWZ(cc, kb));
#pragma unroll
        for (int i = 0; i < 4; ++i) {
          acc[i][n] = mfma_bf16(a_h[i], b_h, acc[i][n]);
          acc[i][n] = mfma_bf16(a_h[i], b_l, acc[i][n]);
          acc[i][n] = mfma_bf16(a_l[i], b_h, acc[i][n]);
        }
      }
    }
  }
#pragma unroll
  for (int i = 0; i < 4; ++i) {
#pragma unroll
    for (int n = 0; n < 2; ++n) {
      int gr0 = row0 + wrow + i * 16 + (lane >> 4) * 4;
      int gc = col0 + wcol + n * 16 + (lane & 15);
#pragma unroll
      for (int q = 0; q < 4; ++q) {
        int gr = gr0 + q;
        if (gr >= N_NODES) continue;
        float v = acc[i][n][q];
        if (gc < 128) ABa[(size_t)gr * 128 + gc] = f2bf(v);
        else ABb[(size_t)gr * 128 + (gc - 128)] = v + bias[gc];
      }
    }
  }
}

// ---------------- fused U GEMM: loop1 = plane0 (k 0..512), loop2 = planes1+2 (k 128..512) ----------------

template <int BN, int LAST>
__global__ __launch_bounds__(256, 3) void k_u_fused(
    const u16* __restrict__ Xh, const u16* __restrict__ Xl,
    const u16* __restrict__ UTh, const u16* __restrict__ UTl,
    const float* __restrict__ Ub, const float* __restrict__ amp,
    const float* __restrict__ att, u16* __restrict__ XhW, u16* __restrict__ XlW,
    float* __restrict__ outF, int Nout) {
  constexpr int NREP = BN / 32;
  constexpr int BE = BN * 64;                     // elems per B array
  constexpr int L1E = 16384 + 2 * BE;             // loop1 footprint
  constexpr int L2E = 8192 + 4 * BE;              // loop2 footprint
  constexpr int LDSE = (L1E > L2E) ? L1E : L2E;
  __shared__ __align__(16) u16 LDS[LDSE];
  u16* Ah  = LDS;                 // [128][64]
  u16* Al  = LDS + 8192;          // loop1 (h steps) only
  u16* B0h = LDS + 16384;         // loop1
  u16* B0l = LDS + 16384 + BE;
  u16* B1h = LDS + 8192;          // loop2 aliases
  u16* B1l = LDS + 8192 + BE;
  u16* B2h = LDS + 8192 + 2 * BE;
  u16* B2l = LDS + 8192 + 3 * BE;

  const int tid = threadIdx.x;
  const int row0 = blockIdx.x * 128;
  const int col0 = blockIdx.y * BN;
  const int lane = tid & 63;
  const int wave = tid >> 6;
  const int wrow = (wave >> 1) * 64;
  const int wcol = (wave & 1) * (BN / 2);

  const u16* U0h = UTh + (size_t)col0 * 512;
  const u16* U0l = UTl + (size_t)col0 * 512;
  const u16* U1h = UTh + (size_t)(Nout + col0) * 512;
  const u16* U1l = UTl + (size_t)(Nout + col0) * 512;
  const u16* U2h = UTh + (size_t)(2 * Nout + col0) * 512;
  const u16* U2l = UTl + (size_t)(2 * Nout + col0) * 512;

  f32x4 acc_t[4][NREP], acc_p1[4][NREP], acc_p2[4][NREP];
  const f32x4 zero4 = {0.f, 0.f, 0.f, 0.f};
#pragma unroll
  for (int i = 0; i < 4; ++i)
#pragma unroll
    for (int n = 0; n < NREP; ++n) {
      acc_t[i][n] = zero4; acc_p1[i][n] = zero4; acc_p2[i][n] = zero4;
    }

  // ---- loop1: plane 0 over k=0..512 (h part 3-prod, agg part 2-prod) ----
  for (int k0 = 0; k0 < 512; k0 += 64) {
    const bool hstep = (k0 < 128);
    __syncthreads();
#pragma unroll
    for (int r = 0; r < 4; ++r) {
      int op = r * 256 + tid;
      int m = op >> 3, ch = op & 7;
      int chx = ch ^ (m & 7);
      int g = row0 + m;
      if (g >= N_NODES) g = N_NODES - 1;
      g2l16(Xh + (size_t)g * 512 + k0 + chx * 8, (char*)Ah + op * 16);
      if (hstep) g2l16(Xl + (size_t)g * 128 + k0 + chx * 8, (char*)Al + op * 16);
    }
#pragma unroll
    for (int r = 0; r < NREP; ++r) {
      int op = r * 256 + tid;
      int c = op >> 3, sl = op & 7;
      int slx = sl ^ (c & 7);
      g2l16(U0h + (size_t)c * 512 + k0 + slx * 8, (char*)B0h + op * 16);
      g2l16(U0l + (size_t)c * 512 + k0 + slx * 8, (char*)B0l + op * 16);
    }
    __syncthreads();
#pragma unroll
    for (int kk = 0; kk < 2; ++kk) {
      const int kb = kk * 64 + (lane >> 4) * 16;
      short8 a_h[4], a_l[4];
#pragma unroll
      for (int i = 0; i < 4; ++i) {
        int rr = wrow + i * 16 + (lane & 15);
        a_h[i] = *(const short8*)((const char*)Ah + SWZ(rr, kb));
        if (hstep) a_l[i] = *(const short8*)((const char*)Al + SWZ(rr, kb));
      }
#pragma unroll
      for (int n = 0; n < NREP; ++n) {
        int cc = wcol + n * 16 + (lane & 15);
        short8 b_h = *(const short8*)((const char*)B0h + SWZ(cc, kb));
        short8 b_l = *(const short8*)((const char*)B0l + SWZ(cc, kb));
#pragma unroll
        for (int i = 0; i < 4; ++i) {
          acc_t[i][n] = mfma_bf16(a_h[i], b_h, acc_t[i][n]);
          acc_t[i][n] = mfma_bf16(a_h[i], b_l, acc_t[i][n]);
          if (hstep) acc_t[i][n] = mfma_bf16(a_l[i], b_h, acc_t[i][n]);
        }
      }
    }
  }

  // ---- loop2: planes 1+2 over k=128..512, A-hi staged ONCE per k-step ----
  for (int k0 = 128; k0 < 512; k0 += 64) {
    __syncthreads();
#pragma unroll
    for (int r = 0; r < 4; ++r) {
      int op = r * 256 + tid;
      int m = op >> 3, ch = op & 7;
      int chx = ch ^ (m & 7);
      int g = row0 + m;
      if (g >= N_NODES) g = N_NODES - 1;
      g2l16(Xh + (size_t)g * 512 + k0 + chx * 8, (char*)Ah + op * 16);
    }
#pragma unroll
    for (int r = 0; r < NREP; ++r) {
      int op = r * 256 + tid;
      int c = op >> 3, sl = op & 7;
      int slx = sl ^ (c & 7);
      size_t so = (size_t)c * 512 + k0 + slx * 8;
      g2l16(U1h + so, (char*)B1h + op * 16);
      g2l16(U1l + so, (char*)B1l + op * 16);
      g2l16(U2h + so, (char*)B2h + op * 16);
      g2l16(U2l + so, (char*)B2l + op * 16);
    }
    __syncthreads();
#pragma unroll
    for (int kk = 0; kk < 2; ++kk) {
      const int kb = kk * 64 + (lane >> 4) * 16;
      short8 a_h[4];
#pragma unroll
      for (int i = 0; i < 4; ++i) {
        int rr = wrow + i * 16 + (lane & 15);
        a_h[i] = *(const short8*)((const char*)Ah + SWZ(rr, kb));
      }
#pragma unroll
      for (int n = 0; n < NREP; ++n) {
        int cc = wcol + n * 16 + (lane & 15);
        short8 b1h = *(const short8*)((const char*)B1h + SWZ(cc, kb));
        short8 b1l = *(const short8*)((const char*)B1l + SWZ(cc, kb));
        short8 b2h = *(const short8*)((const char*)B2h + SWZ(cc, kb));
        short8 b2l = *(const short8*)((const char*)B2l + SWZ(cc, kb));
#pragma unroll
        for (int i = 0; i < 4; ++i) {
          acc_p1[i][n] = mfma_bf16(a_h[i], b1h, acc_p1[i][n]);
          acc_p1[i][n] = mfma_bf16(a_h[i], b1l, acc_p1[i][n]);
          acc_p2[i][n] = mfma_bf16(a_h[i], b2h, acc_p2[i][n]);
          acc_p2[i][n] = mfma_bf16(a_h[i], b2l, acc_p2[i][n]);
        }
      }
    }
  }

  // ---- merge + epilogue ----
#pragma unroll
  for (int i = 0; i < 4; ++i) {
    int gr0 = row0 + wrow + i * 16 + (lane >> 4) * 4;
    f32x4 a1 = *(const f32x4*)(amp + gr0);
    f32x4 a2 = *(const f32x4*)(att + gr0);
#pragma unroll
    for (int n = 0; n < NREP; ++n) {
      int gc = col0 + wcol + n * 16 + (lane & 15);
      float b = Ub[gc];
#pragma unroll
      for (int q = 0; q < 4; ++q) {
        int gr = gr0 + q;
        if (gr >= N_NODES) continue;
        float v = acc_t[i][n][q] + a1[q] * acc_p1[i][n][q] + a2[q] * acc_p2[i][n][q] + b;
        if (LAST) {
          outF[(size_t)gr * 64 + gc] = v;
        } else {
          float t = fmaxf(v, 0.f);
          u16 hi = f2bf(t);
          XhW[(size_t)gr * 512 + gc] = hi;
          XlW[(size_t)gr * 128 + gc] = f2bf(t - bf2f(hi));
        }
      }
    }
  }
}

// ---------------- aggregation: one wave/node. Reads ABa/ABb, WRITES XhDst cols 128..511 ----------------

__global__ __launch_bounds__(256) void k_agg(const u16* __restrict__ ABa,
                                             const float* __restrict__ ABb,
                                             const int* __restrict__ row_off,
                                             const int* __restrict__ nbr,
                                             u16* __restrict__ XhDst) {
  int v = blockIdx.x * 4 + (threadIdx.x >> 6);
  int lane = threadIdx.x & 63;
  if (v >= N_NODES) return;
  int beg = row_off[v], end = row_off[v + 1];
  const u32* A32 = (const u32*)ABa;  // [N][64] u32 (2 bf16 each)
  float sx = 0.f, sy = 0.f;
  float mnx = 3.4e38f, mny = 3.4e38f;
  float mxx = -3.4e38f, mxy = -3.4e38f;
  int i = beg;
#define ACC(w)                                              \
  {                                                         \
    float ax = bf2f((u16)(w)), ay = bf2f((u16)((w) >> 16)); \
    sx += ax; sy += ay;                                     \
    mnx = fminf(mnx, ax); mny = fminf(mny, ay);             \
    mxx = fmaxf(mxx, ax); mxy = fmaxf(mxy, ay);             \
  }
  for (; i + 4 <= end; i += 4) {
    int s0 = nbr[i], s1 = nbr[i + 1], s2 = nbr[i + 2], s3 = nbr[i + 3];
    u32 w0 = A32[(size_t)s0 * 64 + lane];
    u32 w1 = A32[(size_t)s1 * 64 + lane];
    u32 w2 = A32[(size_t)s2 * 64 + lane];
    u32 w3 = A32[(size_t)s3 * 64 + lane];
    ACC(w0) ACC(w1) ACC(w2) ACC(w3)
  }
  for (; i < end; ++i) {
    u32 w = A32[(size_t)nbr[i] * 64 + lane];
    ACC(w)
  }
#undef ACC
  int d = end - beg;
  int c = lane * 2;
  float2 b = *(const float2*)&ABb[(size_t)v * 128 + c];
  float mex, mey, mix, miy, max_, may_;
  if (d > 0) {
    float inv = 1.f / (float)d;
    mex = sx * inv + b.x; mey = sy * inv + b.y;
    mix = mnx + b.x; miy = mny + b.y;
    max_ = mxx + b.x; may_ = mxy + b.y;
  } else {
    mex = mey = mix = miy = max_ = may_ = 0.f;
  }
  u16* xr = XhDst + (size_t)v * 512 + 128 + c;
  *(u32*)(xr)       = pack2bf(mex, mey);
  *(u32*)(xr + 128) = pack2bf(mix, miy);
  *(u32*)(xr + 256) = pack2bf(max_, may_);
}

// ---------------- launch ----------------

extern "C" void kernel_launch(void* const* d_in, const int* in_sizes, int n_in,
                              void* d_out, int out_size, void* d_ws, size_t ws_size,
                              hipStream_t stream) {
  const float* x   = (const float*)d_in[0];
  const int*   src = (const int*)d_in[1];
  const int*   dst = (const int*)d_in[2];
  const float* Mw[3] = {(const float*)d_in[3], (const float*)d_in[7],  (const float*)d_in[11]};
  const float* Mb[3] = {(const float*)d_in[4], (const float*)d_in[8],  (const float*)d_in[12]};
  const float* Uw[3] = {(const float*)d_in[5], (const float*)d_in[9],  (const float*)d_in[13]};
  const float* Ub[3] = {(const float*)d_in[6], (const float*)d_in[10], (const float*)d_in[14]};
  float* out = (float*)d_out;

  char* ws = (char*)d_ws;
  size_t o = 0;
  auto alloc = [&](size_t bytes) -> char* {
    o = (o + 255) & ~(size_t)255;
    char* p = ws + o;
    o += bytes;
    return p;
  };
  int*   deg_i   = (int*)alloc((size_t)N_NODES * 4);
  int*   row_off = (int*)alloc((size_t)(N_NODES + 1) * 4);
  int*   excl    = (int*)alloc((size_t)N_NODES * 4);
  int*   bsum    = (int*)alloc((size_t)NB_SCAN * 4);
  int*   boff    = (int*)alloc((size_t)NB_SCAN * 4);
  int*   cursor  = (int*)alloc((size_t)N_NODES * 4);
  float* amp     = (float*)alloc((size_t)N_NODES * 4);
  float* att     = (float*)alloc((size_t)N_NODES * 4);
  int*   nbr     = (int*)alloc((size_t)N_EDGES * 4);
  u16*   Xh0     = (u16*)alloc((size_t)N_NODES * 512 * 2);   // 51.2 MB
  u16*   Xl0     = (u16*)alloc((size_t)N_NODES * 128 * 2);   // 12.8 MB
  u16*   Xh1     = (u16*)alloc((size_t)N_NODES * 512 * 2);   // 51.2 MB
  u16*   Xl1     = (u16*)alloc((size_t)N_NODES * 128 * 2);   // 12.8 MB
  u16*   ABa     = (u16*)alloc((size_t)N_NODES * 128 * 2);   // 12.8 MB
  float* ABb     = (float*)alloc((size_t)N_NODES * 128 * 4); // 25.6 MB
  u16*   WabTh[3]; u16* WabTl[3]; float* bias_ab[3];
  u16*   UTh[3];   u16* UTl[3];
  const int Nouts[3] = {128, 128, 64};
  for (int L = 0; L < 3; ++L) {
    WabTh[L] = (u16*)alloc((size_t)256 * 128 * 2);
    WabTl[L] = (u16*)alloc((size_t)256 * 128 * 2);
    bias_ab[L] = (float*)alloc(256 * 4);
    UTh[L] = (u16*)alloc((size_t)3 * Nouts[L] * 512 * 2);
    UTl[L] = (u16*)alloc((size_t)3 * Nouts[L] * 512 * 2);
  }

  // ---- graph structure ----
  hipMemsetAsync(deg_i, 0, (size_t)N_NODES * 4, stream);
  k_deg<<<(N_EDGES + 255) / 256, 256, 0, stream>>>(dst, deg_i);
  k_scan_local<<<NB_SCAN, 256, 0, stream>>>(deg_i, excl, bsum);
  k_scan_bsum<<<1, 256, 0, stream>>>(bsum, boff, row_off);
  k_scan_add<<<NB_SCAN, 256, 0, stream>>>(excl, boff, row_off);
  k_node_init<<<(N_NODES + 255) / 256, 256, 0, stream>>>(deg_i, row_off, cursor, amp, att);
  k_fill<<<(N_EDGES + 255) / 256, 256, 0, stream>>>(src, dst, cursor, nbr);

  // ---- weight prep + x pack ----
  for (int L = 0; L < 3; ++L) {
    k_prep_ab<<<256, 128, 0, stream>>>(Mw[L], Mb[L], WabTh[L], WabTl[L], bias_ab[L]);
    k_prep_u<<<dim3(2, Nouts[L], 3), 256, 0, stream>>>(Uw[L], UTh[L], UTl[L], Nouts[L]);
  }
  k_pack_x<<<(N_NODES * DIN + 255) / 256, 256, 0, stream>>>(x, Xh0, Xl0);

  const int MT = (N_NODES + 127) / 128;  // 391
  u16* XhIn[3] = {Xh0, Xh1, Xh0};
  u16* XlIn[3] = {Xl0, Xl1, Xl0};
  u16* XhOut[3] = {Xh1, Xh0, nullptr};
  u16* XlOut[3] = {Xl1, Xl0, nullptr};

  for (int L = 0; L < 3; ++L) {
    k_ab_gemm<<<dim3(MT, 4), 256, 0, stream>>>(XhIn[L], XlIn[L], WabTh[L], WabTl[L],
                                               bias_ab[L], ABa, ABb);
    k_agg<<<(N_NODES + 3) / 4, 256, 0, stream>>>(ABa, ABb, row_off, nbr, XhIn[L]);
    if (L < 2) {
      k_u_fused<64, 0><<<dim3(MT, 2), 256, 0, stream>>>(
          XhIn[L], XlIn[L], UTh[L], UTl[L], Ub[L], amp, att,
          XhOut[L], XlOut[L], nullptr, Nouts[L]);
    } else {
      k_u_fused<32, 1><<<dim3(MT, 2), 256, 0, stream>>>(
          XhIn[L], XlIn[L], UTh[L], UTl[L], Ub[L], amp, att,
          nullptr, nullptr, out, Nouts[L]);
    }
  }
}

// Round 10
// 568.409 us; speedup vs baseline: 1.7277x; 1.0577x over previous
//
#include <hip/hip_runtime.h>
#include <math.h>

#define N_NODES 50000
#define N_EDGES 800000
#define DIN 128
#define NB_SCAN ((N_NODES + 255) / 256)

typedef unsigned short u16;
typedef unsigned int u32;
typedef short short8 __attribute__((ext_vector_type(8)));
typedef float f32x4 __attribute__((ext_vector_type(4)));

__device__ __forceinline__ u16 f2bf(float x) {
  u32 u = __float_as_uint(x);
  u32 r = (u + 0x7FFFu + ((u >> 16) & 1u)) >> 16;
  return (u16)r;
}
__device__ __forceinline__ float bf2f(u16 h) { return __uint_as_float(((u32)h) << 16); }
__device__ __forceinline__ u32 pack2bf(float x, float y) {
  return (u32)f2bf(x) | ((u32)f2bf(y) << 16);
}

__device__ __forceinline__ f32x4 mfma_bf16(short8 a, short8 b, f32x4 c) {
  return __builtin_amdgcn_mfma_f32_16x16x32_bf16(a, b, c, 0, 0, 0);
}

// async global->LDS, 16B per lane. LDS dest must be linear (wave base + lane*16).
__device__ __forceinline__ void g2l16(const void* g, void* l) {
  __builtin_amdgcn_global_load_lds(
      (const __attribute__((address_space(1))) u32*)g,
      (__attribute__((address_space(3))) u32*)l, 16, 0, 0);
}

// swizzled BYTE offset within a [rows][64 bf16] LDS tile (128B rows) — READ side
#define SWZ(row, byt) ((row) * 128 + ((byt) ^ (((row) & 7) << 4)))

// ---------------- graph setup ----------------

__global__ void k_deg(const int* __restrict__ dst, int* __restrict__ deg) {
  int e = blockIdx.x * blockDim.x + threadIdx.x;
  if (e < N_EDGES) atomicAdd(&deg[dst[e]], 1);
}

__global__ void k_scan_local(const int* __restrict__ deg, int* __restrict__ excl,
                             int* __restrict__ bsum) {
  __shared__ int sm[256];
  int tid = threadIdx.x;
  int i = blockIdx.x * 256 + tid;
  int v = (i < N_NODES) ? deg[i] : 0;
  sm[tid] = v;
  __syncthreads();
  for (int off = 1; off < 256; off <<= 1) {
    int t = (tid >= off) ? sm[tid - off] : 0;
    __syncthreads();
    sm[tid] += t;
    __syncthreads();
  }
  if (i < N_NODES) excl[i] = sm[tid] - v;
  if (tid == 255) bsum[blockIdx.x] = sm[255];
}

__global__ void k_scan_bsum(const int* __restrict__ bsum, int* __restrict__ boff,
                            int* __restrict__ row_off) {
  __shared__ int sm[256];
  int tid = threadIdx.x;
  int v = (tid < NB_SCAN) ? bsum[tid] : 0;
  sm[tid] = v;
  __syncthreads();
  for (int off = 1; off < 256; off <<= 1) {
    int t = (tid >= off) ? sm[tid - off] : 0;
    __syncthreads();
    sm[tid] += t;
    __syncthreads();
  }
  if (tid < NB_SCAN) boff[tid] = sm[tid] - v;
  if (tid == 255) row_off[N_NODES] = sm[255];
}

__global__ void k_scan_add(const int* __restrict__ excl, const int* __restrict__ boff,
                           int* __restrict__ row_off) {
  int i = blockIdx.x * 256 + threadIdx.x;
  if (i < N_NODES) row_off[i] = excl[i] + boff[i >> 8];
}

__global__ void k_node_init(const int* __restrict__ deg, const int* __restrict__ row_off,
                            int* __restrict__ cursor, float* __restrict__ amp,
                            float* __restrict__ att) {
  int v = blockIdx.x * blockDim.x + threadIdx.x;
  if (v >= N_NODES) return;
  cursor[v] = row_off[v];
  float d = (float)deg[v];
  float logd = logf(d + 1.0f);
  amp[v] = logd / 3.0f;
  att[v] = 3.0f / fmaxf(logd, 1e-6f);
}

__global__ void k_fill(const int* __restrict__ src, const int* __restrict__ dst,
                       int* __restrict__ cursor, int* __restrict__ nbr) {
  int e = blockIdx.x * blockDim.x + threadIdx.x;
  if (e >= N_EDGES) return;
  int slot = atomicAdd(&cursor[dst[e]], 1);
  nbr[slot] = src[e];
}

// ---------------- weight prep ----------------

// WabT[j][k] = j<128 ? Mw[k][j] : Mw[128+k][j-128]   ([256][128] hi/lo)
__global__ void k_prep_ab(const float* __restrict__ Mw, const float* __restrict__ Mb,
                          u16* __restrict__ Th, u16* __restrict__ Tl,
                          float* __restrict__ bias_ab) {
  int j = blockIdx.x;     // 0..255
  int k = threadIdx.x;    // 0..127
  float w = (j < 128) ? Mw[k * 128 + j] : Mw[(128 + k) * 128 + (j - 128)];
  u16 hi = f2bf(w);
  u16 lo = f2bf(w - bf2f(hi));
  Th[j * 128 + k] = hi;
  Tl[j * 128 + k] = lo;
  if (k == 0) bias_ab[j] = (j < 128) ? 0.f : Mb[j - 128];
}

// UT[p][j][k], k in [0,512): p==0 -> Uw rows 0..511; p>0, k>=128 -> Uw rows 512+384*(p-1)+(k-128)
__global__ void k_prep_u(const float* __restrict__ Uw, u16* __restrict__ Th,
                         u16* __restrict__ Tl, int Nout) {
  int k = blockIdx.x * 256 + threadIdx.x;  // 0..511
  int j = blockIdx.y;
  int p = blockIdx.z;
  if (p > 0 && k < 128) return;
  int srow = (p == 0) ? k : 512 + 384 * (p - 1) + (k - 128);
  float w = Uw[(size_t)srow * Nout + j];
  u16 hi = f2bf(w);
  u16 lo = f2bf(w - bf2f(hi));
  size_t idx = ((size_t)p * Nout + j) * 512 + k;
  Th[idx] = hi;
  Tl[idx] = lo;
}

// ---------------- layer-0 x pack: Xh (hi, stride 512) + Xl (lo, stride 128) ----------------

__global__ void k_pack_x(const float* __restrict__ x, u16* __restrict__ Xh,
                         u16* __restrict__ Xl) {
  int i = blockIdx.x * 256 + threadIdx.x;
  if (i >= N_NODES * DIN) return;
  int g = i >> 7, c = i & 127;
  float v = x[i];
  u16 hi = f2bf(v);
  Xh[(size_t)g * 512 + c] = hi;
  Xl[(size_t)g * 128 + c] = f2bf(v - bf2f(hi));
}

// ---------------- AB GEMM: [N][256] = h @ [Mw_top | Mw_bot], BM=128 BN=64 ----------------
// grid = (4, MT): column tiles adjacent in dispatch order for A-tile L2/L3 reuse.

__global__ __launch_bounds__(256, 3) void k_ab_gemm(
    const u16* __restrict__ Xh, const u16* __restrict__ Xl,
    const u16* __restrict__ WTh, const u16* __restrict__ WTl,
    const float* __restrict__ bias, u16* __restrict__ ABa, float* __restrict__ ABb) {
  __shared__ __align__(16) u16 Ah[128 * 64];
  __shared__ __align__(16) u16 Al[128 * 64];
  __shared__ __align__(16) u16 Bh[64 * 64];
  __shared__ __align__(16) u16 Bl[64 * 64];

  const int tid = threadIdx.x;
  const int row0 = blockIdx.y * 128;
  const int col0 = blockIdx.x * 64;
  const int lane = tid & 63;
  const int wave = tid >> 6;
  const int wrow = (wave >> 1) * 64;
  const int wcol = (wave & 1) * 32;

  f32x4 acc[4][2];
  const f32x4 zero4 = {0.f, 0.f, 0.f, 0.f};
#pragma unroll
  for (int i = 0; i < 4; ++i)
#pragma unroll
    for (int n = 0; n < 2; ++n) acc[i][n] = zero4;

  for (int k0 = 0; k0 < 128; k0 += 64) {
    __syncthreads();
#pragma unroll
    for (int r = 0; r < 4; ++r) {  // A: 128 rows x 8 chunks(16B)
      int op = r * 256 + tid;
      int m = op >> 3, ch = op & 7;
      int chx = ch ^ (m & 7);                 // pre-swizzled source chunk
      int g = row0 + m;
      if (g >= N_NODES) g = N_NODES - 1;      // clamp: junk rows never stored
      g2l16(Xh + (size_t)g * 512 + k0 + chx * 8, (char*)Ah + op * 16);
      g2l16(Xl + (size_t)g * 128 + k0 + chx * 8, (char*)Al + op * 16);
    }
#pragma unroll
    for (int r = 0; r < 2; ++r) {  // B: 64 cols x 8 chunks
      int op = r * 256 + tid;
      int c = op >> 3, sl = op & 7;
      int slx = sl ^ (c & 7);
      g2l16(WTh + (size_t)(col0 + c) * 128 + k0 + slx * 8, (char*)Bh + op * 16);
      g2l16(WTl + (size_t)(col0 + c) * 128 + k0 + slx * 8, (char*)Bl + op * 16);
    }
    __syncthreads();
#pragma unroll
    for (int kk = 0; kk < 2; ++kk) {
      const int kb = kk * 64 + (lane >> 4) * 16;
      short8 a_h[4], a_l[4];
#pragma unroll
      for (int i = 0; i < 4; ++i) {
        int rr = wrow + i * 16 + (lane & 15);
        a_h[i] = *(const short8*)((const char*)Ah + SWZ(rr, kb));
        a_l[i] = *(const short8*)((const char*)Al + SWZ(rr, kb));
      }
#pragma unroll
      for (int n = 0; n < 2; ++n) {
        int cc = wcol + n * 16 + (lane & 15);
        short8 b_h = *(const short8*)((const char*)Bh + SWZ(cc, kb));
        short8 b_l = *(const short8*)((const char*)Bl + SWZ(cc, kb));
#pragma unroll
        for (int i = 0; i < 4; ++i) {
          acc[i][n] = mfma_bf16(a_h[i], b_h, acc[i][n]);
          acc[i][n] = mfma_bf16(a_h[i], b_l, acc[i][n]);
          acc[i][n] = mfma_bf16(a_l[i], b_h, acc[i][n]);
        }
      }
    }
  }
#pragma unroll
  for (int i = 0; i < 4; ++i) {
#pragma unroll
    for (int n = 0; n < 2; ++n) {
      int gr0 = row0 + wrow + i * 16 + (lane >> 4) * 4;
      int gc = col0 + wcol + n * 16 + (lane & 15);
#pragma unroll
      for (int q = 0; q < 4; ++q) {
        int gr = gr0 + q;
        if (gr >= N_NODES) continue;
        float v = acc[i][n][q];
        if (gc < 128) ABa[(size_t)gr * 128 + gc] = f2bf(v);
        else ABb[(size_t)gr * 128 + (gc - 128)] = v + bias[gc];
      }
    }
  }
}

// ---------------- fused U GEMM, merged single k-loop ----------------
// k<128: A(hi+lo) + B0 (plane0, 3-prod). k>=128: A(hi) + B0,B1,B2 (2-prod each).
// Al aliases the B1/B2 LDS region (disjoint k-phases). grid = (NC, MT).

template <int BN, int LAST>
__global__ __launch_bounds__(256, 2) void k_u_fused(
    const u16* __restrict__ Xh, const u16* __restrict__ Xl,
    const u16* __restrict__ UTh, const u16* __restrict__ UTl,
    const float* __restrict__ Ub, const float* __restrict__ amp,
    const float* __restrict__ att, u16* __restrict__ XhW, u16* __restrict__ XlW,
    float* __restrict__ outF, int Nout) {
  constexpr int NREP = BN / 32;
  constexpr int BE = BN * 64;                 // elems per B array
  constexpr int LDSE = 8192 + 2 * BE + ((4 * BE > 8192) ? 4 * BE : 8192);
  __shared__ __align__(16) u16 LDS[LDSE];
  u16* Ah  = LDS;
  u16* B0h = LDS + 8192;
  u16* B0l = LDS + 8192 + BE;
  u16* B1h = LDS + 8192 + 2 * BE;
  u16* B1l = LDS + 8192 + 3 * BE;
  u16* B2h = LDS + 8192 + 4 * BE;
  u16* B2l = LDS + 8192 + 5 * BE;
  u16* Al  = LDS + 8192 + 2 * BE;             // alias (k<128 only)

  const int tid = threadIdx.x;
  const int row0 = blockIdx.y * 128;
  const int col0 = blockIdx.x * BN;
  const int lane = tid & 63;
  const int wave = tid >> 6;
  const int wrow = (wave >> 1) * 64;
  const int wcol = (wave & 1) * (BN / 2);

  const u16* U0h = UTh + (size_t)col0 * 512;
  const u16* U0l = UTl + (size_t)col0 * 512;
  const u16* U1h = UTh + (size_t)(Nout + col0) * 512;
  const u16* U1l = UTl + (size_t)(Nout + col0) * 512;
  const u16* U2h = UTh + (size_t)(2 * Nout + col0) * 512;
  const u16* U2l = UTl + (size_t)(2 * Nout + col0) * 512;

  f32x4 acc_t[4][NREP], acc_p1[4][NREP], acc_p2[4][NREP];
  const f32x4 zero4 = {0.f, 0.f, 0.f, 0.f};
#pragma unroll
  for (int i = 0; i < 4; ++i)
#pragma unroll
    for (int n = 0; n < NREP; ++n) {
      acc_t[i][n] = zero4; acc_p1[i][n] = zero4; acc_p2[i][n] = zero4;
    }

  for (int k0 = 0; k0 < 512; k0 += 64) {
    const bool hstep = (k0 < 128);
    __syncthreads();
    // ---- stage A (hi always, lo on h-steps) ----
#pragma unroll
    for (int r = 0; r < 4; ++r) {
      int op = r * 256 + tid;
      int m = op >> 3, ch = op & 7;
      int chx = ch ^ (m & 7);
      int g = row0 + m;
      if (g >= N_NODES) g = N_NODES - 1;
      g2l16(Xh + (size_t)g * 512 + k0 + chx * 8, (char*)Ah + op * 16);
      if (hstep) g2l16(Xl + (size_t)g * 128 + k0 + chx * 8, (char*)Al + op * 16);
    }
    // ---- stage B: plane0 always; planes 1+2 on agg-steps ----
#pragma unroll
    for (int r = 0; r < NREP; ++r) {
      int op = r * 256 + tid;
      int c = op >> 3, sl = op & 7;
      int slx = sl ^ (c & 7);
      size_t so = (size_t)c * 512 + k0 + slx * 8;
      g2l16(U0h + so, (char*)B0h + op * 16);
      g2l16(U0l + so, (char*)B0l + op * 16);
      if (!hstep) {
        g2l16(U1h + so, (char*)B1h + op * 16);
        g2l16(U1l + so, (char*)B1l + op * 16);
        g2l16(U2h + so, (char*)B2h + op * 16);
        g2l16(U2l + so, (char*)B2l + op * 16);
      }
    }
    __syncthreads();
    // ---- MFMA ----
#pragma unroll
    for (int kk = 0; kk < 2; ++kk) {
      const int kb = kk * 64 + (lane >> 4) * 16;
      short8 a_h[4], a_l[4];
#pragma unroll
      for (int i = 0; i < 4; ++i) {
        int rr = wrow + i * 16 + (lane & 15);
        a_h[i] = *(const short8*)((const char*)Ah + SWZ(rr, kb));
        if (hstep) a_l[i] = *(const short8*)((const char*)Al + SWZ(rr, kb));
      }
#pragma unroll
      for (int n = 0; n < NREP; ++n) {
        int cc = wcol + n * 16 + (lane & 15);
        short8 b0h = *(const short8*)((const char*)B0h + SWZ(cc, kb));
        short8 b0l = *(const short8*)((const char*)B0l + SWZ(cc, kb));
#pragma unroll
        for (int i = 0; i < 4; ++i) {
          acc_t[i][n] = mfma_bf16(a_h[i], b0h, acc_t[i][n]);
          acc_t[i][n] = mfma_bf16(a_h[i], b0l, acc_t[i][n]);
          if (hstep) acc_t[i][n] = mfma_bf16(a_l[i], b0h, acc_t[i][n]);
        }
        if (!hstep) {
          short8 b1h = *(const short8*)((const char*)B1h + SWZ(cc, kb));
          short8 b1l = *(const short8*)((const char*)B1l + SWZ(cc, kb));
          short8 b2h = *(const short8*)((const char*)B2h + SWZ(cc, kb));
          short8 b2l = *(const short8*)((const char*)B2l + SWZ(cc, kb));
#pragma unroll
          for (int i = 0; i < 4; ++i) {
            acc_p1[i][n] = mfma_bf16(a_h[i], b1h, acc_p1[i][n]);
            acc_p1[i][n] = mfma_bf16(a_h[i], b1l, acc_p1[i][n]);
            acc_p2[i][n] = mfma_bf16(a_h[i], b2h, acc_p2[i][n]);
            acc_p2[i][n] = mfma_bf16(a_h[i], b2l, acc_p2[i][n]);
          }
        }
      }
    }
  }

  // ---- merge + epilogue ----
#pragma unroll
  for (int i = 0; i < 4; ++i) {
    int gr0 = row0 + wrow + i * 16 + (lane >> 4) * 4;
    f32x4 a1 = *(const f32x4*)(amp + gr0);
    f32x4 a2 = *(const f32x4*)(att + gr0);
#pragma unroll
    for (int n = 0; n < NREP; ++n) {
      int gc = col0 + wcol + n * 16 + (lane & 15);
      float b = Ub[gc];
#pragma unroll
      for (int q = 0; q < 4; ++q) {
        int gr = gr0 + q;
        if (gr >= N_NODES) continue;
        float v = acc_t[i][n][q] + a1[q] * acc_p1[i][n][q] + a2[q] * acc_p2[i][n][q] + b;
        if (LAST) {
          outF[(size_t)gr * 64 + gc] = v;
        } else {
          float t = fmaxf(v, 0.f);
          u16 hi = f2bf(t);
          XhW[(size_t)gr * 512 + gc] = hi;
          XlW[(size_t)gr * 128 + gc] = f2bf(t - bf2f(hi));
        }
      }
    }
  }
}

// ---------------- aggregation: 4 nodes/wave, 16 lanes/node, uint4 gather ----------------
// XhDst row = 512 u16 = 64 uint4. mean -> u16 128..255 = uint4 16..31,
// min -> 256..383 = uint4 32..47, max -> 384..511 = uint4 48..63.

__global__ __launch_bounds__(256) void k_agg(const u16* __restrict__ ABa,
                                             const float* __restrict__ ABb,
                                             const int* __restrict__ row_off,
                                             const int* __restrict__ nbr,
                                             u16* __restrict__ XhDst) {
  int wv = blockIdx.x * 4 + (threadIdx.x >> 6);
  int lane = threadIdx.x & 63;
  int grp = lane >> 4;        // node within wave
  int sub = lane & 15;        // 16 lanes per node, 8 channels each
  int v = wv * 4 + grp;
  if (v >= N_NODES) return;
  int beg = row_off[v], end = row_off[v + 1];
  const uint4* A16 = (const uint4*)ABa;  // row = 16 uint4 (128 bf16)
  float s[8], mn[8], mx[8];
#pragma unroll
  for (int c = 0; c < 8; ++c) { s[c] = 0.f; mn[c] = 3.4e38f; mx[c] = -3.4e38f; }
  for (int i = beg; i < end; ++i) {
    int sidx = nbr[i];
    uint4 w = A16[(size_t)sidx * 16 + sub];
    u32 ww[4] = {w.x, w.y, w.z, w.w};
#pragma unroll
    for (int j = 0; j < 4; ++j) {
      float ax = bf2f((u16)ww[j]), ay = bf2f((u16)(ww[j] >> 16));
      s[2 * j] += ax; s[2 * j + 1] += ay;
      mn[2 * j] = fminf(mn[2 * j], ax); mn[2 * j + 1] = fminf(mn[2 * j + 1], ay);
      mx[2 * j] = fmaxf(mx[2 * j], ax); mx[2 * j + 1] = fmaxf(mx[2 * j + 1], ay);
    }
  }
  int d = end - beg;
  float bb[8];
  {
    f32x4 b0 = *(const f32x4*)(ABb + (size_t)v * 128 + sub * 8);
    f32x4 b1 = *(const f32x4*)(ABb + (size_t)v * 128 + sub * 8 + 4);
#pragma unroll
    for (int c = 0; c < 4; ++c) { bb[c] = b0[c]; bb[4 + c] = b1[c]; }
  }
  uint4 wm, wn, wx;
  u32* pm = &wm.x; u32* pn = &wn.x; u32* px = &wx.x;
  if (d > 0) {
    float inv = 1.f / (float)d;
#pragma unroll
    for (int j = 0; j < 4; ++j) {
      pm[j] = pack2bf(s[2 * j] * inv + bb[2 * j], s[2 * j + 1] * inv + bb[2 * j + 1]);
      pn[j] = pack2bf(mn[2 * j] + bb[2 * j], mn[2 * j + 1] + bb[2 * j + 1]);
      px[j] = pack2bf(mx[2 * j] + bb[2 * j], mx[2 * j + 1] + bb[2 * j + 1]);
    }
  } else {
#pragma unroll
    for (int j = 0; j < 4; ++j) { pm[j] = 0u; pn[j] = 0u; px[j] = 0u; }
  }
  uint4* xr = (uint4*)(XhDst + (size_t)v * 512);
  xr[16 + sub] = wm;   // mean: u16 cols 128..255
  xr[32 + sub] = wn;   // min : 256..383
  xr[48 + sub] = wx;   // max : 384..511
}

// ---------------- launch ----------------

extern "C" void kernel_launch(void* const* d_in, const int* in_sizes, int n_in,
                              void* d_out, int out_size, void* d_ws, size_t ws_size,
                              hipStream_t stream) {
  const float* x   = (const float*)d_in[0];
  const int*   src = (const int*)d_in[1];
  const int*   dst = (const int*)d_in[2];
  const float* Mw[3] = {(const float*)d_in[3], (const float*)d_in[7],  (const float*)d_in[11]};
  const float* Mb[3] = {(const float*)d_in[4], (const float*)d_in[8],  (const float*)d_in[12]};
  const float* Uw[3] = {(const float*)d_in[5], (const float*)d_in[9],  (const float*)d_in[13]};
  const float* Ub[3] = {(const float*)d_in[6], (const float*)d_in[10], (const float*)d_in[14]};
  float* out = (float*)d_out;

  char* ws = (char*)d_ws;
  size_t o = 0;
  auto alloc = [&](size_t bytes) -> char* {
    o = (o + 255) & ~(size_t)255;
    char* p = ws + o;
    o += bytes;
    return p;
  };
  int*   deg_i   = (int*)alloc((size_t)N_NODES * 4);
  int*   row_off = (int*)alloc((size_t)(N_NODES + 1) * 4);
  int*   excl    = (int*)alloc((size_t)N_NODES * 4);
  int*   bsum    = (int*)alloc((size_t)NB_SCAN * 4);
  int*   boff    = (int*)alloc((size_t)NB_SCAN * 4);
  int*   cursor  = (int*)alloc((size_t)N_NODES * 4);
  float* amp     = (float*)alloc((size_t)N_NODES * 4);
  float* att     = (float*)alloc((size_t)N_NODES * 4);
  int*   nbr     = (int*)alloc((size_t)N_EDGES * 4);
  u16*   Xh0     = (u16*)alloc((size_t)N_NODES * 512 * 2);   // 51.2 MB
  u16*   Xl0     = (u16*)alloc((size_t)N_NODES * 128 * 2);   // 12.8 MB
  u16*   Xh1     = (u16*)alloc((size_t)N_NODES * 512 * 2);   // 51.2 MB
  u16*   Xl1     = (u16*)alloc((size_t)N_NODES * 128 * 2);   // 12.8 MB
  u16*   ABa     = (u16*)alloc((size_t)N_NODES * 128 * 2);   // 12.8 MB
  float* ABb     = (float*)alloc((size_t)N_NODES * 128 * 4); // 25.6 MB
  u16*   WabTh[3]; u16* WabTl[3]; float* bias_ab[3];
  u16*   UTh[3];   u16* UTl[3];
  const int Nouts[3] = {128, 128, 64};
  for (int L = 0; L < 3; ++L) {
    WabTh[L] = (u16*)alloc((size_t)256 * 128 * 2);
    WabTl[L] = (u16*)alloc((size_t)256 * 128 * 2);
    bias_ab[L] = (float*)alloc(256 * 4);
    UTh[L] = (u16*)alloc((size_t)3 * Nouts[L] * 512 * 2);
    UTl[L] = (u16*)alloc((size_t)3 * Nouts[L] * 512 * 2);
  }

  // ---- graph structure ----
  hipMemsetAsync(deg_i, 0, (size_t)N_NODES * 4, stream);
  k_deg<<<(N_EDGES + 255) / 256, 256, 0, stream>>>(dst, deg_i);
  k_scan_local<<<NB_SCAN, 256, 0, stream>>>(deg_i, excl, bsum);
  k_scan_bsum<<<1, 256, 0, stream>>>(bsum, boff, row_off);
  k_scan_add<<<NB_SCAN, 256, 0, stream>>>(excl, boff, row_off);
  k_node_init<<<(N_NODES + 255) / 256, 256, 0, stream>>>(deg_i, row_off, cursor, amp, att);
  k_fill<<<(N_EDGES + 255) / 256, 256, 0, stream>>>(src, dst, cursor, nbr);

  // ---- weight prep + x pack ----
  for (int L = 0; L < 3; ++L) {
    k_prep_ab<<<256, 128, 0, stream>>>(Mw[L], Mb[L], WabTh[L], WabTl[L], bias_ab[L]);
    k_prep_u<<<dim3(2, Nouts[L], 3), 256, 0, stream>>>(Uw[L], UTh[L], UTl[L], Nouts[L]);
  }
  k_pack_x<<<(N_NODES * DIN + 255) / 256, 256, 0, stream>>>(x, Xh0, Xl0);

  const int MT = (N_NODES + 127) / 128;  // 391
  u16* XhIn[3] = {Xh0, Xh1, Xh0};
  u16* XlIn[3] = {Xl0, Xl1, Xl0};
  u16* XhOut[3] = {Xh1, Xh0, nullptr};
  u16* XlOut[3] = {Xl1, Xl0, nullptr};

  for (int L = 0; L < 3; ++L) {
    k_ab_gemm<<<dim3(4, MT), 256, 0, stream>>>(XhIn[L], XlIn[L], WabTh[L], WabTl[L],
                                               bias_ab[L], ABa, ABb);
    k_agg<<<(N_NODES + 15) / 16, 256, 0, stream>>>(ABa, ABb, row_off, nbr, XhIn[L]);
    if (L < 2) {
      k_u_fused<64, 0><<<dim3(2, MT), 256, 0, stream>>>(
          XhIn[L], XlIn[L], UTh[L], UTl[L], Ub[L], amp, att,
          XhOut[L], XlOut[L], nullptr, Nouts[L]);
    } else {
      k_u_fused<32, 1><<<dim3(2, MT), 256, 0, stream>>>(
          XhIn[L], XlIn[L], UTh[L], UTl[L], Ub[L], amp, att,
          nullptr, nullptr, out, Nouts[L]);
    }
  }
}